// Round 1
// baseline (1320.227 us; speedup 1.0000x reference)
//
#include <hip/hip_runtime.h>
#include <math.h>

// Problem constants
// B=2, S=2048, D_MODEL=1024, D_KV=64, N_HEADS=16, KV_HEADS=4, G=4
// scores[b,h,n,s] = sum_d (sum_g q[b,g*4+h,n,d]) * (mean_g k[b,g*4+h,s,d]) + gbias
// attn = softmax(scores); ctx[b, g*4+h, n, :] = attn_h @ V_{g*4+h}; out = ctx @ Wo

// ---------------- prep: reduced weights ----------------
__global__ __launch_bounds__(256) void prep_weights(const float* __restrict__ Wq,
                                                    const float* __restrict__ Wk,
                                                    float* __restrict__ Wqs,
                                                    float* __restrict__ Wkm) {
    int idx = blockIdx.x * 256 + threadIdx.x;   // 1024*256
    int d = idx >> 8;
    int col = idx & 255;          // h*64 + j
    int h = col >> 6, j = col & 63;
    float sq = 0.f, sk = 0.f;
#pragma unroll
    for (int g = 0; g < 4; ++g) {
        int e = (g * 4 + h) * 64 + j;
        sq += Wq[(size_t)d * 1024 + e];
        sk += Wk[(size_t)d * 1024 + e];
    }
    Wqs[idx] = sq;
    Wkm[idx] = sk * 0.25f;
}

// ---------------- prep: relative-position bias table ----------------
// table[delta+2047][h] = mean_g rel_bias[bucket(delta), g*4+h]
__global__ __launch_bounds__(256) void prep_bias(const float* __restrict__ rel_bias,
                                                 float* __restrict__ table) {
    int idx = blockIdx.x * 256 + threadIdx.x;
    if (idx >= 4095) return;
    int delta = idx - 2047;     // mem - ctx
    int bucket = (delta > 0) ? 16 : 0;
    int arp = delta < 0 ? -delta : delta;
    int rb;
    if (arp < 8) {
        rb = arp;
    } else {
        // mirror reference f32 math: log(rp/8)/log(16)*8
        float tt = (logf((float)arp * 0.125f) / 2.772588722239781f) * 8.0f;
        int ri = 8 + (int)tt;
        rb = ri < 15 ? ri : 15;
    }
    bucket += rb;
#pragma unroll
    for (int h = 0; h < 4; ++h) {
        float s = 0.25f * (rel_bias[bucket * 16 + h] + rel_bias[bucket * 16 + h + 4] +
                           rel_bias[bucket * 16 + h + 8] + rel_bias[bucket * 16 + h + 12]);
        table[idx * 4 + h] = s;
    }
}

// ---------------- generic fp32 tiled GEMM: C[M,N] = A[M,K] @ B[K,N] ----------------
// 64x64 tile, BK=16, 256 threads, 4x4 per thread
__global__ __launch_bounds__(256) void gemm_f32(const float* __restrict__ A,
                                                const float* __restrict__ B,
                                                float* __restrict__ C,
                                                int M, int N, int K) {
    __shared__ __align__(16) float As[16][68];  // [k][m]
    __shared__ __align__(16) float Bs[16][68];  // [k][n]
    int t = threadIdx.x;
    int tx = t & 15, ty = t >> 4;
    int m0 = blockIdx.y * 64, n0 = blockIdx.x * 64;
    int r0 = ty * 4, c0 = tx * 4;
    float acc[4][4] = {};

    int arow = t >> 2, akk = (t & 3) * 4;
    int brow = t >> 4, bcol = (t & 15) * 4;

    for (int k0 = 0; k0 < K; k0 += 16) {
        float4 a4 = *(const float4*)(A + (size_t)(m0 + arow) * K + k0 + akk);
        As[akk + 0][arow] = a4.x;
        As[akk + 1][arow] = a4.y;
        As[akk + 2][arow] = a4.z;
        As[akk + 3][arow] = a4.w;
        *(float4*)&Bs[brow][bcol] = *(const float4*)(B + (size_t)(k0 + brow) * N + n0 + bcol);
        __syncthreads();
#pragma unroll
        for (int kk = 0; kk < 16; ++kk) {
            float4 av = *(const float4*)&As[kk][r0];
            float4 bv = *(const float4*)&Bs[kk][c0];
            float a[4] = {av.x, av.y, av.z, av.w};
            float b[4] = {bv.x, bv.y, bv.z, bv.w};
#pragma unroll
            for (int i = 0; i < 4; ++i)
#pragma unroll
                for (int j = 0; j < 4; ++j) acc[i][j] += a[i] * b[j];
        }
        __syncthreads();
    }
#pragma unroll
    for (int i = 0; i < 4; ++i) {
        float4 o = make_float4(acc[i][0], acc[i][1], acc[i][2], acc[i][3]);
        *(float4*)(C + (size_t)(m0 + r0 + i) * N + n0 + c0) = o;
    }
}

// ---------------- flash attention per (b, kv-head, 64-query tile) ----------------
// Qr/Kr: [B*S, 256] (4 kv-heads x 64), V: [B*S, 1024] (16 heads x 64)
// ctx: [B*S, 1024]
__global__ __launch_bounds__(256) void attn_kernel(const float* __restrict__ Qr,
                                                   const float* __restrict__ Kr,
                                                   const float* __restrict__ V,
                                                   const float* __restrict__ btab,
                                                   float* __restrict__ ctx) {
    __shared__ __align__(16) float Qs[64][68];
    __shared__ __align__(16) float Ks[64][68];
    __shared__ __align__(16) float Ps[64][65];
    __shared__ float m_s[64], l_s[64], sc_s[64];

    int t = threadIdx.x;
    int blk = blockIdx.x;
    int qt = blk & 31;
    int h = (blk >> 5) & 3;
    int b = blk >> 7;
    int n0 = qt * 64;

    // load Q tile [64 rows x 64 dims]
    const float* Qbase = Qr + ((size_t)(b * 2048 + n0)) * 256 + h * 64;
#pragma unroll
    for (int i = 0; i < 4; ++i) {
        int id = t + i * 256;
        int row = id >> 4, col = (id & 15) * 4;
        *(float4*)&Qs[row][col] = *(const float4*)(Qbase + (size_t)row * 256 + col);
    }
    if (t < 64) {
        m_s[t] = -INFINITY;
        l_s[t] = 0.f;
    }

    // score-phase mapping: 16x16 threads, 4x4 each
    int tx = t & 15, ty = t >> 4;
    int r0 = ty * 4, c0 = tx * 4;
    // O-phase mapping: wave = g; lane owns 16 rows x 4 cols
    int lane = t & 63;
    int wid = t >> 6;                 // g
    int orow0 = (lane >> 4) * 16;
    int ocol0 = (lane & 15) * 4;

    float O[16][4] = {};

    const float* Kbase = Kr + ((size_t)(b * 2048)) * 256 + h * 64;
    const float* Vbase = V + ((size_t)(b * 2048)) * 1024 + (wid * 4 + h) * 64 + ocol0;

    for (int s0 = 0; s0 < 2048; s0 += 64) {
        // load K tile
#pragma unroll
        for (int i = 0; i < 4; ++i) {
            int id = t + i * 256;
            int row = id >> 4, col = (id & 15) * 4;
            *(float4*)&Ks[row][col] = *(const float4*)(Kbase + (size_t)(s0 + row) * 256 + col);
        }
        __syncthreads();

        // scores 4x4
        float s[4][4] = {};
#pragma unroll
        for (int d = 0; d < 64; d += 4) {
            float4 q[4], k4[4];
#pragma unroll
            for (int i = 0; i < 4; ++i) q[i] = *(const float4*)&Qs[r0 + i][d];
#pragma unroll
            for (int j = 0; j < 4; ++j) k4[j] = *(const float4*)&Ks[c0 + j][d];
#pragma unroll
            for (int i = 0; i < 4; ++i)
#pragma unroll
                for (int j = 0; j < 4; ++j)
                    s[i][j] += q[i].x * k4[j].x + q[i].y * k4[j].y + q[i].z * k4[j].z +
                               q[i].w * k4[j].w;
        }
        // bias add: delta = (s0+c0+j) - (n0+r0+i)
        int dbase = (s0 + c0) - (n0 + r0) + 2047;
#pragma unroll
        for (int i = 0; i < 4; ++i)
#pragma unroll
            for (int j = 0; j < 4; ++j) s[i][j] += btab[(size_t)(dbase + j - i) * 4 + h];

        // row max (reduce over j, then over tx group = 16 lanes in-wave)
        float rm[4];
#pragma unroll
        for (int i = 0; i < 4; ++i)
            rm[i] = fmaxf(fmaxf(s[i][0], s[i][1]), fmaxf(s[i][2], s[i][3]));
#pragma unroll
        for (int off = 1; off < 16; off <<= 1)
#pragma unroll
            for (int i = 0; i < 4; ++i) rm[i] = fmaxf(rm[i], __shfl_xor(rm[i], off, 64));

        float mold[4], mnew[4], rs[4];
#pragma unroll
        for (int i = 0; i < 4; ++i) {
            mold[i] = m_s[r0 + i];
            mnew[i] = fmaxf(mold[i], rm[i]);
            rs[i] = 0.f;
        }
#pragma unroll
        for (int i = 0; i < 4; ++i)
#pragma unroll
            for (int j = 0; j < 4; ++j) {
                float p = __expf(s[i][j] - mnew[i]);
                s[i][j] = p;
                rs[i] += p;
            }
#pragma unroll
        for (int off = 1; off < 16; off <<= 1)
#pragma unroll
            for (int i = 0; i < 4; ++i) rs[i] += __shfl_xor(rs[i], off, 64);

        // write P tile
#pragma unroll
        for (int i = 0; i < 4; ++i)
#pragma unroll
            for (int j = 0; j < 4; ++j) Ps[r0 + i][c0 + j] = s[i][j];

        if (tx == 0) {
#pragma unroll
            for (int i = 0; i < 4; ++i) {
                float scale = __expf(mold[i] - mnew[i]);   // first tile: exp(-inf)=0
                sc_s[r0 + i] = scale;
                m_s[r0 + i] = mnew[i];
                l_s[r0 + i] = l_s[r0 + i] * scale + rs[i];
            }
        }
        __syncthreads();

        // O update: O[16][4] += P @ V_g  (V from global, L2/L3 resident)
#pragma unroll
        for (int ii = 0; ii < 16; ++ii) {
            float sc = sc_s[orow0 + ii];
            O[ii][0] *= sc; O[ii][1] *= sc; O[ii][2] *= sc; O[ii][3] *= sc;
        }
        const float* vp = Vbase + (size_t)s0 * 1024;
#pragma unroll 4
        for (int k = 0; k < 64; ++k) {
            float4 v4 = *(const float4*)(vp + (size_t)k * 1024);
#pragma unroll
            for (int ii = 0; ii < 16; ++ii) {
                float p = Ps[orow0 + ii][k];
                O[ii][0] += p * v4.x;
                O[ii][1] += p * v4.y;
                O[ii][2] += p * v4.z;
                O[ii][3] += p * v4.w;
            }
        }
        __syncthreads();
    }

    // epilogue: divide by l, store ctx
#pragma unroll
    for (int ii = 0; ii < 16; ++ii) {
        float inv = 1.f / l_s[orow0 + ii];
        float4 o = make_float4(O[ii][0] * inv, O[ii][1] * inv, O[ii][2] * inv, O[ii][3] * inv);
        *(float4*)(ctx + ((size_t)(b * 2048 + n0 + orow0 + ii)) * 1024 + (wid * 4 + h) * 64 +
                   ocol0) = o;
    }
}

extern "C" void kernel_launch(void* const* d_in, const int* in_sizes, int n_in,
                              void* d_out, int out_size, void* d_ws, size_t ws_size,
                              hipStream_t stream) {
    const float* hs = (const float*)d_in[0];   // [2,2048,1024]
    const float* Wq = (const float*)d_in[1];   // [1024,1024]
    const float* Wk = (const float*)d_in[2];
    const float* Wv = (const float*)d_in[3];
    const float* Wo = (const float*)d_in[4];
    const float* rb = (const float*)d_in[5];   // [32,16]
    float* out = (float*)d_out;                // [2,2048,1024]

    float* ws = (float*)d_ws;
    float* Wqs = ws;                 // 1024*256
    float* Wkm = Wqs + 262144;       // 1024*256
    float* btab = Wkm + 262144;      // 4095*4 (padded to 16384)
    float* Qr = btab + 16384;        // 4096*256
    float* Kr = Qr + 1048576;        // 4096*256
    float* V = Kr + 1048576;         // 4096*1024
    float* ctx = V + 4194304;        // 4096*1024
    // total ws use: ~44.1 MB

    prep_weights<<<1024, 256, 0, stream>>>(Wq, Wk, Wqs, Wkm);
    prep_bias<<<16, 256, 0, stream>>>(rb, btab);

    gemm_f32<<<dim3(4, 64), 256, 0, stream>>>(hs, Wqs, Qr, 4096, 256, 1024);
    gemm_f32<<<dim3(4, 64), 256, 0, stream>>>(hs, Wkm, Kr, 4096, 256, 1024);
    gemm_f32<<<dim3(16, 64), 256, 0, stream>>>(hs, Wv, V, 4096, 1024, 1024);

    attn_kernel<<<256, 256, 0, stream>>>(Qr, Kr, V, btab, ctx);

    gemm_f32<<<dim3(16, 64), 256, 0, stream>>>(ctx, Wo, out, 4096, 1024, 1024);
}

// Round 2
// 396.208 us; speedup vs baseline: 3.3322x; 3.3322x over previous
//
#include <hip/hip_runtime.h>
#include <math.h>

// B=2, S=2048, D_MODEL=1024, D_KV=64, N_HEADS=16, KV_HEADS=4, G=4
// Pipeline (all heavy math on bf16 MFMA, fp32 accumulate):
//   cast hs -> hi/lo bf16; reduce Wq(sum_g)/Wk(mean_g) -> WqkT hi/lo bf16 [512][1024]
//   QK proj (hi/lo split GEMM, fp32-grade scores) -> QKhi/QKlo bf16 [4096][512]
//   VT = WvT @ hs^T  (bf16 GEMM, output transposed [1024][4096])
//   flash attention (MFMA QK^T + online softmax + MFMA PV) -> ctx bf16 [4096][1024]
//   out = ctx @ Wo (bf16 GEMM, fp32 out)

typedef __bf16 bf16_t;
typedef bf16_t bf16x8 __attribute__((ext_vector_type(8)));
typedef bf16_t bf16x4 __attribute__((ext_vector_type(4)));
typedef float f32x4 __attribute__((ext_vector_type(4)));

#define MFMA16(a, b, c) __builtin_amdgcn_mfma_f32_16x16x32_bf16(a, b, c, 0, 0, 0)

typedef __attribute__((address_space(1))) void gvoid;
typedef __attribute__((address_space(3))) void svoid;
__device__ __forceinline__ void gld16(const void* g, void* l) {
    __builtin_amdgcn_global_load_lds((gvoid*)g, (svoid*)l, 16, 0, 0);
}

// ---------------- prep: cast hs to hi/lo bf16 ----------------
__global__ __launch_bounds__(256) void cast_hs(const float* __restrict__ x,
                                               bf16_t* __restrict__ hi,
                                               bf16_t* __restrict__ lo) {
    size_t idx = ((size_t)blockIdx.x * 256 + threadIdx.x) * 4;
    float4 v = *(const float4*)(x + idx);
    bf16x4 h, l;
    h[0] = (bf16_t)v.x; l[0] = (bf16_t)(v.x - (float)h[0]);
    h[1] = (bf16_t)v.y; l[1] = (bf16_t)(v.y - (float)h[1]);
    h[2] = (bf16_t)v.z; l[2] = (bf16_t)(v.z - (float)h[2]);
    h[3] = (bf16_t)v.w; l[3] = (bf16_t)(v.w - (float)h[3]);
    *(bf16x4*)(hi + idx) = h;
    *(bf16x4*)(lo + idx) = l;
}

// ---------------- prep: reduced QK weights, transposed, hi/lo ----------------
// Thi/Tlo [512][1024]: rows 0..255 = (sum_g Wq)^T cols, rows 256..511 = (mean_g Wk)^T
__global__ __launch_bounds__(256) void prep_wqk(const float* __restrict__ Wq,
                                                const float* __restrict__ Wk,
                                                bf16_t* __restrict__ Thi,
                                                bf16_t* __restrict__ Tlo) {
    __shared__ float rq[1024], rk[1024];
    int k = blockIdx.x, t = threadIdx.x;
#pragma unroll
    for (int j = 0; j < 4; ++j) {
        rq[t + j * 256] = Wq[(size_t)k * 1024 + t + j * 256];
        rk[t + j * 256] = Wk[(size_t)k * 1024 + t + j * 256];
    }
    __syncthreads();
    int h = t >> 6, j2 = t & 63;
    float sq = 0.f, sk = 0.f;
#pragma unroll
    for (int g = 0; g < 4; ++g) {
        sq += rq[(g * 4 + h) * 64 + j2];
        sk += rk[(g * 4 + h) * 64 + j2];
    }
    sk *= 0.25f;
    bf16_t qh = (bf16_t)sq;
    Thi[(size_t)t * 1024 + k] = qh;
    Tlo[(size_t)t * 1024 + k] = (bf16_t)(sq - (float)qh);
    bf16_t kh = (bf16_t)sk;
    Thi[(size_t)(256 + t) * 1024 + k] = kh;
    Tlo[(size_t)(256 + t) * 1024 + k] = (bf16_t)(sk - (float)kh);
}

// ---------------- prep: transpose 1024x1024 f32 -> bf16 ----------------
__global__ __launch_bounds__(256) void transpose_to_bf16(const float* __restrict__ src,
                                                         bf16_t* __restrict__ dst) {
    __shared__ float tile[32][33];
    int tx = threadIdx.x & 31, ty = threadIdx.x >> 5;
    int bx = blockIdx.x * 32, by = blockIdx.y * 32;
#pragma unroll
    for (int i = 0; i < 32; i += 8)
        tile[ty + i][tx] = src[(size_t)(by + ty + i) * 1024 + bx + tx];
    __syncthreads();
#pragma unroll
    for (int i = 0; i < 32; i += 8)
        dst[(size_t)(bx + ty + i) * 1024 + by + tx] = (bf16_t)tile[tx][ty + i];
}

// ---------------- prep: relative-position bias table ----------------
__global__ __launch_bounds__(256) void prep_bias(const float* __restrict__ rel_bias,
                                                 float* __restrict__ table) {
    int idx = blockIdx.x * 256 + threadIdx.x;
    if (idx >= 4095) return;
    int delta = idx - 2047;  // mem - ctx
    int bucket = (delta > 0) ? 16 : 0;
    int arp = delta < 0 ? -delta : delta;
    int rb;
    if (arp < 8) {
        rb = arp;
    } else {
        float tt = (logf((float)arp * 0.125f) / 2.772588722239781f) * 8.0f;
        int ri = 8 + (int)tt;
        rb = ri < 15 ? ri : 15;
    }
    bucket += rb;
#pragma unroll
    for (int h = 0; h < 4; ++h) {
        float s = 0.25f * (rel_bias[bucket * 16 + h] + rel_bias[bucket * 16 + h + 4] +
                           rel_bias[bucket * 16 + h + 8] + rel_bias[bucket * 16 + h + 12]);
        table[idx * 4 + h] = s;
    }
}

// ---------------- bf16 MFMA GEMM: C[M,N] = A[M,K] * BT[N,K]^T ----------------
// 128x128 tile, BK=32, 256 threads (4 waves, each 64x64), dbuf LDS, global_load_lds x16.
// LDS chunk layout: slot = chunk(k/8)*128 + row; each slot = 8 bf16 (16 B).
template <int BF16_OUT>
__global__ __launch_bounds__(256, 1) void gemm_mfma(const bf16_t* __restrict__ A,
                                                    const bf16_t* __restrict__ BT,
                                                    void* __restrict__ Cv,
                                                    int M, int N, int K) {
    __shared__ bf16_t As[2][4096];
    __shared__ bf16_t Bs[2][4096];
    const int t = threadIdx.x;
    const int w = t >> 6, lane = t & 63;
    const int lr = lane & 15, q = lane >> 4;
    const int m0 = blockIdx.y * 128, n0 = blockIdx.x * 128;
    const int mw = (w & 1) * 64, nw = (w >> 1) * 64;
    f32x4 acc[4][4] = {};
    const int nk = K >> 5;

    const int s0i = t, s1i = 256 + t;
    const int c0 = s0i >> 7, r0 = s0i & 127;
    const int c1 = s1i >> 7, r1 = s1i & 127;
    const bf16_t* gA0 = A + (size_t)(m0 + r0) * K + c0 * 8;
    const bf16_t* gA1 = A + (size_t)(m0 + r1) * K + c1 * 8;
    const bf16_t* gB0 = BT + (size_t)(n0 + r0) * K + c0 * 8;
    const bf16_t* gB1 = BT + (size_t)(n0 + r1) * K + c1 * 8;
    const int ldsA = (w * 64) * 8, ldsB = (256 + w * 64) * 8;

    auto stage = [&](int bf, int k0) {
        gld16(gA0 + k0, &As[bf][ldsA]);
        gld16(gA1 + k0, &As[bf][ldsB]);
        gld16(gB0 + k0, &Bs[bf][ldsA]);
        gld16(gB1 + k0, &Bs[bf][ldsB]);
    };

    stage(0, 0);
    __syncthreads();
    for (int it = 0; it < nk; ++it) {
        const int cur = it & 1;
        if (it + 1 < nk) stage(cur ^ 1, (it + 1) * 32);
        bf16x8 af[4], bfv[4];
#pragma unroll
        for (int i = 0; i < 4; ++i)
            af[i] = *(const bf16x8*)&As[cur][(q * 128 + mw + i * 16 + lr) * 8];
#pragma unroll
        for (int j = 0; j < 4; ++j)
            bfv[j] = *(const bf16x8*)&Bs[cur][(q * 128 + nw + j * 16 + lr) * 8];
#pragma unroll
        for (int i = 0; i < 4; ++i)
#pragma unroll
            for (int j = 0; j < 4; ++j) acc[i][j] = MFMA16(af[i], bfv[j], acc[i][j]);
        __syncthreads();
    }

#pragma unroll
    for (int i = 0; i < 4; ++i) {
        int row = m0 + mw + i * 16 + q * 4;
#pragma unroll
        for (int j = 0; j < 4; ++j) {
            int col = n0 + nw + j * 16 + lr;
#pragma unroll
            for (int reg = 0; reg < 4; ++reg) {
                if (BF16_OUT)
                    ((bf16_t*)Cv)[(size_t)(row + reg) * N + col] = (bf16_t)acc[i][j][reg];
                else
                    ((float*)Cv)[(size_t)(row + reg) * N + col] = acc[i][j][reg];
            }
        }
    }
}

// ---------------- hi/lo split GEMM for QK projection (fp32-grade) ----------------
// C = (Ah+Al)(Bh+Bl)^T ~= Ah*Bh + Ah*Bl + Al*Bh ; outputs hi/lo bf16 pair.
__global__ __launch_bounds__(256, 1) void gemm_qk(const bf16_t* __restrict__ Ah,
                                                  const bf16_t* __restrict__ Al,
                                                  const bf16_t* __restrict__ Bh,
                                                  const bf16_t* __restrict__ Bl,
                                                  bf16_t* __restrict__ Chi,
                                                  bf16_t* __restrict__ Clo,
                                                  int M, int N, int K) {
    __shared__ bf16_t AsH[2][4096], AsL[2][4096], BsH[2][4096], BsL[2][4096];
    const int t = threadIdx.x;
    const int w = t >> 6, lane = t & 63;
    const int lr = lane & 15, q = lane >> 4;
    const int m0 = blockIdx.y * 128, n0 = blockIdx.x * 128;
    const int mw = (w & 1) * 64, nw = (w >> 1) * 64;
    f32x4 acc[4][4] = {};
    const int nk = K >> 5;

    const int s0i = t, s1i = 256 + t;
    const int c0 = s0i >> 7, r0 = s0i & 127;
    const int c1 = s1i >> 7, r1 = s1i & 127;
    const size_t oA0 = (size_t)(m0 + r0) * K + c0 * 8;
    const size_t oA1 = (size_t)(m0 + r1) * K + c1 * 8;
    const size_t oB0 = (size_t)(n0 + r0) * K + c0 * 8;
    const size_t oB1 = (size_t)(n0 + r1) * K + c1 * 8;
    const int ldsA = (w * 64) * 8, ldsB = (256 + w * 64) * 8;

    auto stage = [&](int bf, int k0) {
        gld16(Ah + oA0 + k0, &AsH[bf][ldsA]);
        gld16(Ah + oA1 + k0, &AsH[bf][ldsB]);
        gld16(Al + oA0 + k0, &AsL[bf][ldsA]);
        gld16(Al + oA1 + k0, &AsL[bf][ldsB]);
        gld16(Bh + oB0 + k0, &BsH[bf][ldsA]);
        gld16(Bh + oB1 + k0, &BsH[bf][ldsB]);
        gld16(Bl + oB0 + k0, &BsL[bf][ldsA]);
        gld16(Bl + oB1 + k0, &BsL[bf][ldsB]);
    };

    stage(0, 0);
    __syncthreads();
    for (int it = 0; it < nk; ++it) {
        const int cur = it & 1;
        if (it + 1 < nk) stage(cur ^ 1, (it + 1) * 32);
        bf16x8 ah[4], al[4], bh[4], bl[4];
#pragma unroll
        for (int i = 0; i < 4; ++i) {
            int sa = (q * 128 + mw + i * 16 + lr) * 8;
            ah[i] = *(const bf16x8*)&AsH[cur][sa];
            al[i] = *(const bf16x8*)&AsL[cur][sa];
        }
#pragma unroll
        for (int j = 0; j < 4; ++j) {
            int sb = (q * 128 + nw + j * 16 + lr) * 8;
            bh[j] = *(const bf16x8*)&BsH[cur][sb];
            bl[j] = *(const bf16x8*)&BsL[cur][sb];
        }
#pragma unroll
        for (int i = 0; i < 4; ++i)
#pragma unroll
            for (int j = 0; j < 4; ++j) {
                acc[i][j] = MFMA16(ah[i], bh[j], acc[i][j]);
                acc[i][j] = MFMA16(ah[i], bl[j], acc[i][j]);
                acc[i][j] = MFMA16(al[i], bh[j], acc[i][j]);
            }
        __syncthreads();
    }

#pragma unroll
    for (int i = 0; i < 4; ++i) {
        int row = m0 + mw + i * 16 + q * 4;
#pragma unroll
        for (int j = 0; j < 4; ++j) {
            int col = n0 + nw + j * 16 + lr;
#pragma unroll
            for (int reg = 0; reg < 4; ++reg) {
                float x = acc[i][j][reg];
                bf16_t hi = (bf16_t)x;
                size_t o = (size_t)(row + reg) * N + col;
                Chi[o] = hi;
                Clo[o] = (bf16_t)(x - (float)hi);
            }
        }
    }
}

// ---------------- flash attention, bf16 MFMA ----------------
// grid 256 = b(2) x h(4) x qtile(32 of 64 rows); block 256 (4 waves x 16 q-rows).
// QKhi/lo [4096][512] (cols 0..255 = Q, 256..511 = K); VT [1024][4096]; ctx [4096][1024].
// LDS chunk layouts (slot = 16 B = 8 bf16):
//   Kh/Kl: slot = dchunk(0..7)*64 + s(0..63)          (8 KB each)
//   Vs   : slot = schunk(0..7)*256 + vcol(0..255)      (32 KB)
//   Ps   : per-wave 128 slots: w*128 + schunk(0..7)*16 + qrow(0..15)  (8 KB)
__global__ __launch_bounds__(256, 1) void attn_mfma(const bf16_t* __restrict__ QKhi,
                                                    const bf16_t* __restrict__ QKlo,
                                                    const bf16_t* __restrict__ VT,
                                                    const float* __restrict__ btab,
                                                    bf16_t* __restrict__ ctx) {
    __shared__ bf16_t Kh[4096], Kl[4096], Vsm[16384], Ps[4096];
    const int t = threadIdx.x, w = t >> 6, lane = t & 63;
    const int lr = lane & 15, q = lane >> 4;
    const int blk = blockIdx.x;
    const int qt = blk & 31, h = (blk >> 5) & 3, b = blk >> 7;
    const int n0 = qt * 64;
    const int rowbase = n0 + w * 16;  // within batch

    // Q fragments (hi/lo), kept in registers: row = lane&15, k-chunk = kb*4+q
    const size_t qrow = (size_t)(b * 2048 + rowbase + lr) * 512 + h * 64;
    bf16x8 aqh[2], aql[2];
#pragma unroll
    for (int kb = 0; kb < 2; ++kb) {
        aqh[kb] = *(const bf16x8*)(QKhi + qrow + kb * 32 + q * 8);
        aql[kb] = *(const bf16x8*)(QKlo + qrow + kb * 32 + q * 8);
    }

    // staging pointers
    const int ks0 = t, ks1 = 256 + t;
    const int kc0 = ks0 >> 6, kr0 = ks0 & 63;
    const int kc1 = ks1 >> 6, kr1 = ks1 & 63;
    const bf16_t* gK0 = QKhi + (size_t)(b * 2048 + kr0) * 512 + 256 + h * 64 + kc0 * 8;
    const bf16_t* gK1 = QKhi + (size_t)(b * 2048 + kr1) * 512 + 256 + h * 64 + kc1 * 8;
    const bf16_t* gL0 = QKlo + (size_t)(b * 2048 + kr0) * 512 + 256 + h * 64 + kc0 * 8;
    const bf16_t* gL1 = QKlo + (size_t)(b * 2048 + kr1) * 512 + 256 + h * 64 + kc1 * 8;
    const bf16_t* gV[8];
#pragma unroll
    for (int j = 0; j < 8; ++j) {
        int slot = j * 256 + t;
        int c = slot >> 8, v = slot & 255;
        int vg = ((v >> 6) * 4 + h) * 64 + (v & 63);
        gV[j] = VT + (size_t)vg * 4096 + b * 2048 + c * 8;
    }
    const int ldsK0 = (w * 64) * 8, ldsK1 = (256 + w * 64) * 8;

    float m_r[4], l_r[4];
#pragma unroll
    for (int reg = 0; reg < 4; ++reg) { m_r[reg] = -INFINITY; l_r[reg] = 0.f; }
    f32x4 O[16] = {};

    for (int it = 0; it < 32; ++it) {
        const int s0 = it * 64;
        // stage K (hi/lo) and V tiles
        gld16(gK0 + (size_t)s0 * 512, &Kh[ldsK0]);
        gld16(gK1 + (size_t)s0 * 512, &Kh[ldsK1]);
        gld16(gL0 + (size_t)s0 * 512, &Kl[ldsK0]);
        gld16(gL1 + (size_t)s0 * 512, &Kl[ldsK1]);
#pragma unroll
        for (int j = 0; j < 8; ++j) gld16(gV[j] + s0, &Vsm[(j * 256 + w * 64) * 8]);
        __syncthreads();

        // scores: S[16 rows][64 cols] per wave, hi/lo split (3 MFMAs per k-block)
        f32x4 sc[4];
#pragma unroll
        for (int ct = 0; ct < 4; ++ct) {
            f32x4 z = {0.f, 0.f, 0.f, 0.f};
#pragma unroll
            for (int kb = 0; kb < 2; ++kb) {
                int sb = ((kb * 4 + q) * 64 + ct * 16 + lr) * 8;
                bf16x8 bh = *(const bf16x8*)&Kh[sb];
                bf16x8 bl = *(const bf16x8*)&Kl[sb];
                z = MFMA16(aqh[kb], bh, z);
                z = MFMA16(aqh[kb], bl, z);
                z = MFMA16(aql[kb], bh, z);
            }
            sc[ct] = z;
        }
        // bias: delta = (s0+ct*16+lr) - (rowbase+q*4+reg)
        const int colg = s0 + lr, rowg = rowbase + q * 4;
#pragma unroll
        for (int ct = 0; ct < 4; ++ct)
#pragma unroll
            for (int reg = 0; reg < 4; ++reg)
                sc[ct][reg] += btab[(size_t)(colg + ct * 16 - rowg - reg + 2047) * 4 + h];

        // online softmax (rows fully wave-local; 16-lane col groups per quad)
        float rm[4];
#pragma unroll
        for (int reg = 0; reg < 4; ++reg)
            rm[reg] = fmaxf(fmaxf(sc[0][reg], sc[1][reg]), fmaxf(sc[2][reg], sc[3][reg]));
#pragma unroll
        for (int off = 1; off < 16; off <<= 1)
#pragma unroll
            for (int reg = 0; reg < 4; ++reg)
                rm[reg] = fmaxf(rm[reg], __shfl_xor(rm[reg], off, 64));

        float alpha[4], rs[4];
#pragma unroll
        for (int reg = 0; reg < 4; ++reg) {
            float mo = m_r[reg];
            float mn = fmaxf(mo, rm[reg]);
            alpha[reg] = __expf(mo - mn);  // first tile: exp(-inf)=0
            m_r[reg] = mn;
            rs[reg] = 0.f;
        }
#pragma unroll
        for (int ct = 0; ct < 4; ++ct) {
#pragma unroll
            for (int reg = 0; reg < 4; ++reg) {
                float p = __expf(sc[ct][reg] - m_r[reg]);
                rs[reg] += p;
                int col = ct * 16 + lr;
                Ps[((w * 128 + (col >> 3) * 16) + q * 4 + reg) * 8 + (col & 7)] = (bf16_t)p;
            }
        }
#pragma unroll
        for (int off = 1; off < 16; off <<= 1)
#pragma unroll
            for (int reg = 0; reg < 4; ++reg) rs[reg] += __shfl_xor(rs[reg], off, 64);
#pragma unroll
        for (int reg = 0; reg < 4; ++reg) l_r[reg] = l_r[reg] * alpha[reg] + rs[reg];

        // P A-fragments (wave-private LDS region; intra-wave ordering via lgkmcnt)
        bf16x8 pa[2];
#pragma unroll
        for (int kb = 0; kb < 2; ++kb)
            pa[kb] = *(const bf16x8*)&Ps[(w * 128 + (kb * 4 + q) * 16 + lr) * 8];

        // O = alpha*O + P @ V
#pragma unroll
        for (int nt = 0; nt < 16; ++nt) {
            f32x4 o = O[nt];
#pragma unroll
            for (int reg = 0; reg < 4; ++reg) o[reg] *= alpha[reg];
#pragma unroll
            for (int kb = 0; kb < 2; ++kb) {
                bf16x8 v = *(const bf16x8*)&Vsm[((kb * 4 + q) * 256 + nt * 16 + lr) * 8];
                o = MFMA16(pa[kb], v, o);
            }
            O[nt] = o;
        }
        __syncthreads();
    }

    // epilogue
    float inv[4];
#pragma unroll
    for (int reg = 0; reg < 4; ++reg) inv[reg] = 1.f / l_r[reg];
    const size_t tokbase = (size_t)(b * 2048 + rowbase + q * 4);
#pragma unroll
    for (int nt = 0; nt < 16; ++nt) {
        int v = nt * 16 + lr;
        int vg = ((v >> 6) * 4 + h) * 64 + (v & 63);
#pragma unroll
        for (int reg = 0; reg < 4; ++reg)
            ctx[(tokbase + reg) * 1024 + vg] = (bf16_t)(O[nt][reg] * inv[reg]);
    }
}

extern "C" void kernel_launch(void* const* d_in, const int* in_sizes, int n_in,
                              void* d_out, int out_size, void* d_ws, size_t ws_size,
                              hipStream_t stream) {
    const float* hs = (const float*)d_in[0];
    const float* Wq = (const float*)d_in[1];
    const float* Wk = (const float*)d_in[2];
    const float* Wv = (const float*)d_in[3];
    const float* Wo = (const float*)d_in[4];
    const float* rb = (const float*)d_in[5];
    float* out = (float*)d_out;

    char* ws = (char*)d_ws;
    bf16_t* hs_hi = (bf16_t*)(ws);                       // 8 MB; reused as ctx
    bf16_t* hs_lo = (bf16_t*)(ws + (8 << 20));           // 8 MB; reused as VT
    bf16_t* WqkThi = (bf16_t*)(ws + (16 << 20));         // 1 MB
    bf16_t* WqkTlo = (bf16_t*)(ws + (17 << 20));         // 1 MB
    bf16_t* WvT = (bf16_t*)(ws + (18 << 20));            // 2 MB
    bf16_t* WoT = (bf16_t*)(ws + (20 << 20));            // 2 MB
    float* btab = (float*)(ws + (22 << 20));             // 64 KB
    bf16_t* QKhi = (bf16_t*)(ws + (22 << 20) + 65536);   // 4 MB
    bf16_t* QKlo = QKhi + (size_t)4096 * 512;            // 4 MB  (total ~30 MB)
    bf16_t* VT = hs_lo;   // alias: hs_lo dead after gemm_qk
    bf16_t* ctx = hs_hi;  // alias: hs_hi dead after VT GEMM

    cast_hs<<<4096, 256, 0, stream>>>(hs, hs_hi, hs_lo);
    prep_wqk<<<1024, 256, 0, stream>>>(Wq, Wk, WqkThi, WqkTlo);
    transpose_to_bf16<<<dim3(32, 32), 256, 0, stream>>>(Wv, WvT);
    transpose_to_bf16<<<dim3(32, 32), 256, 0, stream>>>(Wo, WoT);
    prep_bias<<<16, 256, 0, stream>>>(rb, btab);

    // QK projection, hi/lo split: [4096][512]
    gemm_qk<<<dim3(4, 32), 256, 0, stream>>>(hs_hi, hs_lo, WqkThi, WqkTlo, QKhi, QKlo,
                                             4096, 512, 1024);
    // VT[1024][4096] = WvT[1024][1024] * hs[4096][1024]^T
    gemm_mfma<1><<<dim3(32, 8), 256, 0, stream>>>(WvT, hs_hi, VT, 1024, 4096, 1024);
    // attention -> ctx bf16 [4096][1024]
    attn_mfma<<<256, 256, 0, stream>>>(QKhi, QKlo, VT, btab, ctx);
    // out[4096][1024] = ctx * WoT^T (fp32 out)
    gemm_mfma<0><<<dim3(8, 32), 256, 0, stream>>>(ctx, WoT, out, 4096, 1024, 1024);
}

// Round 3
// 313.119 us; speedup vs baseline: 4.2164x; 1.2654x over previous
//
#include <hip/hip_runtime.h>
#include <math.h>

// B=2, S=2048, D_MODEL=1024, D_KV=64, N_HEADS=16, KV_HEADS=4, G=4
// Pipeline (bf16 MFMA, fp32 accumulate):
//   cast hs -> hi/lo bf16; Wq(sum_g)/Wk(mean_g) -> WqkT hi/lo [512][1024]
//   gemm_qk -> Q hi/lo [4096][256] row-major + K hi/lo in BLOCKED per-(b,h,it) tiles
//   V GEMM  -> V in BLOCKED per-(b,h,it) tiles (LDS slot order, coalesced staging)
//   attn: dbuf LDS staging (all gld16 fully coalesced) + MFMA QK^T/PV + online softmax
//   out = ctx @ Wo (bf16 MFMA, fp32 out)

typedef __bf16 bf16_t;
typedef bf16_t bf16x8 __attribute__((ext_vector_type(8)));
typedef bf16_t bf16x4 __attribute__((ext_vector_type(4)));
typedef float f32x4 __attribute__((ext_vector_type(4)));

#define MFMA16(a, b, c) __builtin_amdgcn_mfma_f32_16x16x32_bf16(a, b, c, 0, 0, 0)

typedef __attribute__((address_space(1))) void gvoid;
typedef __attribute__((address_space(3))) void svoid;
__device__ __forceinline__ void gld16(const void* g, void* l) {
    __builtin_amdgcn_global_load_lds((gvoid*)g, (svoid*)l, 16, 0, 0);
}

// ---------------- prep: cast hs to hi/lo bf16 ----------------
__global__ __launch_bounds__(256) void cast_hs(const float* __restrict__ x,
                                               bf16_t* __restrict__ hi,
                                               bf16_t* __restrict__ lo) {
    size_t idx = ((size_t)blockIdx.x * 256 + threadIdx.x) * 4;
    float4 v = *(const float4*)(x + idx);
    bf16x4 h, l;
    h[0] = (bf16_t)v.x; l[0] = (bf16_t)(v.x - (float)h[0]);
    h[1] = (bf16_t)v.y; l[1] = (bf16_t)(v.y - (float)h[1]);
    h[2] = (bf16_t)v.z; l[2] = (bf16_t)(v.z - (float)h[2]);
    h[3] = (bf16_t)v.w; l[3] = (bf16_t)(v.w - (float)h[3]);
    *(bf16x4*)(hi + idx) = h;
    *(bf16x4*)(lo + idx) = l;
}

// ---------------- prep: reduced QK weights, transposed, hi/lo ----------------
__global__ __launch_bounds__(256) void prep_wqk(const float* __restrict__ Wq,
                                                const float* __restrict__ Wk,
                                                bf16_t* __restrict__ Thi,
                                                bf16_t* __restrict__ Tlo) {
    __shared__ float rq[1024], rk[1024];
    int k = blockIdx.x, t = threadIdx.x;
#pragma unroll
    for (int j = 0; j < 4; ++j) {
        rq[t + j * 256] = Wq[(size_t)k * 1024 + t + j * 256];
        rk[t + j * 256] = Wk[(size_t)k * 1024 + t + j * 256];
    }
    __syncthreads();
    int h = t >> 6, j2 = t & 63;
    float sq = 0.f, sk = 0.f;
#pragma unroll
    for (int g = 0; g < 4; ++g) {
        sq += rq[(g * 4 + h) * 64 + j2];
        sk += rk[(g * 4 + h) * 64 + j2];
    }
    sk *= 0.25f;
    bf16_t qh = (bf16_t)sq;
    Thi[(size_t)t * 1024 + k] = qh;
    Tlo[(size_t)t * 1024 + k] = (bf16_t)(sq - (float)qh);
    bf16_t kh = (bf16_t)sk;
    Thi[(size_t)(256 + t) * 1024 + k] = kh;
    Tlo[(size_t)(256 + t) * 1024 + k] = (bf16_t)(sk - (float)kh);
}

// ---------------- prep: transpose 1024x1024 f32 -> bf16 ----------------
__global__ __launch_bounds__(256) void transpose_to_bf16(const float* __restrict__ src,
                                                         bf16_t* __restrict__ dst) {
    __shared__ float tile[32][33];
    int tx = threadIdx.x & 31, ty = threadIdx.x >> 5;
    int bx = blockIdx.x * 32, by = blockIdx.y * 32;
#pragma unroll
    for (int i = 0; i < 32; i += 8)
        tile[ty + i][tx] = src[(size_t)(by + ty + i) * 1024 + bx + tx];
    __syncthreads();
#pragma unroll
    for (int i = 0; i < 32; i += 8)
        dst[(size_t)(bx + ty + i) * 1024 + by + tx] = (bf16_t)tile[tx][ty + i];
}

// ---------------- prep: bias table, layout [4 heads][4608] ----------------
__global__ __launch_bounds__(256) void prep_bias(const float* __restrict__ rel_bias,
                                                 float* __restrict__ table) {
    int idx = blockIdx.x * 256 + threadIdx.x;
    if (idx >= 4095) return;
    int delta = idx - 2047;  // mem - ctx
    int bucket = (delta > 0) ? 16 : 0;
    int arp = delta < 0 ? -delta : delta;
    int rb;
    if (arp < 8) {
        rb = arp;
    } else {
        float tt = (logf((float)arp * 0.125f) / 2.772588722239781f) * 8.0f;
        int ri = 8 + (int)tt;
        rb = ri < 15 ? ri : 15;
    }
    bucket += rb;
#pragma unroll
    for (int h = 0; h < 4; ++h) {
        float s = 0.25f * (rel_bias[bucket * 16 + h] + rel_bias[bucket * 16 + h + 4] +
                           rel_bias[bucket * 16 + h + 8] + rel_bias[bucket * 16 + h + 12]);
        table[h * 4608 + idx] = s;
    }
}

// ---------------- bf16 MFMA GEMM: C[M,N] = A[M,K] * BT[N,K]^T ----------------
// MODE 0: f32 row-major out. MODE 2: bf16 V-blocked out (per-(b,h,it) 32KB tiles,
//         slot = schunk*256 + g*64 + d, 8 tokens per slot).
template <int MODE>
__global__ __launch_bounds__(256, 1) void gemm_mfma(const bf16_t* __restrict__ A,
                                                    const bf16_t* __restrict__ BT,
                                                    void* __restrict__ Cv,
                                                    int M, int N, int K) {
    __shared__ bf16_t As[2][4096];
    __shared__ bf16_t Bs[2][4096];
    const int t = threadIdx.x;
    const int w = t >> 6, lane = t & 63;
    const int lr = lane & 15, q = lane >> 4;
    const int m0 = blockIdx.y * 128, n0 = blockIdx.x * 128;
    const int mw = (w & 1) * 64, nw = (w >> 1) * 64;
    f32x4 acc[4][4] = {};
    const int nk = K >> 5;

    const int s0i = t, s1i = 256 + t;
    const int c0 = s0i >> 7, r0 = s0i & 127;
    const int c1 = s1i >> 7, r1 = s1i & 127;
    const bf16_t* gA0 = A + (size_t)(m0 + r0) * K + c0 * 8;
    const bf16_t* gA1 = A + (size_t)(m0 + r1) * K + c1 * 8;
    const bf16_t* gB0 = BT + (size_t)(n0 + r0) * K + c0 * 8;
    const bf16_t* gB1 = BT + (size_t)(n0 + r1) * K + c1 * 8;
    const int ldsA = (w * 64) * 8, ldsB = (256 + w * 64) * 8;

    auto stage = [&](int bf, int k0) {
        gld16(gA0 + k0, &As[bf][ldsA]);
        gld16(gA1 + k0, &As[bf][ldsB]);
        gld16(gB0 + k0, &Bs[bf][ldsA]);
        gld16(gB1 + k0, &Bs[bf][ldsB]);
    };

    stage(0, 0);
    __syncthreads();
    for (int it = 0; it < nk; ++it) {
        const int cur = it & 1;
        if (it + 1 < nk) stage(cur ^ 1, (it + 1) * 32);
        bf16x8 af[4], bfv[4];
#pragma unroll
        for (int i = 0; i < 4; ++i)
            af[i] = *(const bf16x8*)&As[cur][(q * 128 + mw + i * 16 + lr) * 8];
#pragma unroll
        for (int j = 0; j < 4; ++j)
            bfv[j] = *(const bf16x8*)&Bs[cur][(q * 128 + nw + j * 16 + lr) * 8];
#pragma unroll
        for (int i = 0; i < 4; ++i)
#pragma unroll
            for (int j = 0; j < 4; ++j) acc[i][j] = MFMA16(af[i], bfv[j], acc[i][j]);
        __syncthreads();
    }

#pragma unroll
    for (int i = 0; i < 4; ++i) {
        int row = m0 + mw + i * 16 + q * 4;
#pragma unroll
        for (int j = 0; j < 4; ++j) {
            int col = n0 + nw + j * 16 + lr;
#pragma unroll
            for (int reg = 0; reg < 4; ++reg) {
                if (MODE == 0) {
                    ((float*)Cv)[(size_t)(row + reg) * N + col] = acc[i][j][reg];
                } else {
                    // row = vg (0..1023), col = token (0..4095)
                    int vg = row + reg;
                    int hd = vg >> 6, d = vg & 63;
                    int h = hd & 3, g = hd >> 2;
                    int b = col >> 11, s = col & 2047;
                    int it2 = s >> 6, sc = (s >> 3) & 7, si = s & 7;
                    size_t o = ((size_t)((b * 4 + h) * 32 + it2)) * 16384 +
                               (size_t)(sc * 256 + g * 64 + d) * 8 + si;
                    ((bf16_t*)Cv)[o] = (bf16_t)acc[i][j][reg];
                }
            }
        }
    }
}

// ---------------- hi/lo split GEMM for QK projection ----------------
// Writes Q rows [4096][256] hi/lo + K blocked per-(b,h,it) 8KB tiles
// (slot = dchunk*64 + s, 8 dims per slot).
__global__ __launch_bounds__(256, 1) void gemm_qk(const bf16_t* __restrict__ Ah,
                                                  const bf16_t* __restrict__ Al,
                                                  const bf16_t* __restrict__ Bh,
                                                  const bf16_t* __restrict__ Bl,
                                                  bf16_t* __restrict__ Qhi,
                                                  bf16_t* __restrict__ Qlo,
                                                  bf16_t* __restrict__ Kbh,
                                                  bf16_t* __restrict__ Kbl,
                                                  int K) {
    __shared__ bf16_t AsH[2][4096], AsL[2][4096], BsH[2][4096], BsL[2][4096];
    const int t = threadIdx.x;
    const int w = t >> 6, lane = t & 63;
    const int lr = lane & 15, q = lane >> 4;
    const int m0 = blockIdx.y * 128, n0 = blockIdx.x * 128;
    const int mw = (w & 1) * 64, nw = (w >> 1) * 64;
    f32x4 acc[4][4] = {};
    const int nk = K >> 5;

    const int s0i = t, s1i = 256 + t;
    const int c0 = s0i >> 7, r0 = s0i & 127;
    const int c1 = s1i >> 7, r1 = s1i & 127;
    const size_t oA0 = (size_t)(m0 + r0) * K + c0 * 8;
    const size_t oA1 = (size_t)(m0 + r1) * K + c1 * 8;
    const size_t oB0 = (size_t)(n0 + r0) * K + c0 * 8;
    const size_t oB1 = (size_t)(n0 + r1) * K + c1 * 8;
    const int ldsA = (w * 64) * 8, ldsB = (256 + w * 64) * 8;

    auto stage = [&](int bf, int k0) {
        gld16(Ah + oA0 + k0, &AsH[bf][ldsA]);
        gld16(Ah + oA1 + k0, &AsH[bf][ldsB]);
        gld16(Al + oA0 + k0, &AsL[bf][ldsA]);
        gld16(Al + oA1 + k0, &AsL[bf][ldsB]);
        gld16(Bh + oB0 + k0, &BsH[bf][ldsA]);
        gld16(Bh + oB1 + k0, &BsH[bf][ldsB]);
        gld16(Bl + oB0 + k0, &BsL[bf][ldsA]);
        gld16(Bl + oB1 + k0, &BsL[bf][ldsB]);
    };

    stage(0, 0);
    __syncthreads();
    for (int it = 0; it < nk; ++it) {
        const int cur = it & 1;
        if (it + 1 < nk) stage(cur ^ 1, (it + 1) * 32);
        bf16x8 ah[4], al[4], bh[4], bl[4];
#pragma unroll
        for (int i = 0; i < 4; ++i) {
            int sa = (q * 128 + mw + i * 16 + lr) * 8;
            ah[i] = *(const bf16x8*)&AsH[cur][sa];
            al[i] = *(const bf16x8*)&AsL[cur][sa];
        }
#pragma unroll
        for (int j = 0; j < 4; ++j) {
            int sb = (q * 128 + nw + j * 16 + lr) * 8;
            bh[j] = *(const bf16x8*)&BsH[cur][sb];
            bl[j] = *(const bf16x8*)&BsL[cur][sb];
        }
#pragma unroll
        for (int i = 0; i < 4; ++i)
#pragma unroll
            for (int j = 0; j < 4; ++j) {
                acc[i][j] = MFMA16(ah[i], bh[j], acc[i][j]);
                acc[i][j] = MFMA16(ah[i], bl[j], acc[i][j]);
                acc[i][j] = MFMA16(al[i], bh[j], acc[i][j]);
            }
        __syncthreads();
    }

#pragma unroll
    for (int i = 0; i < 4; ++i) {
        int row = m0 + mw + i * 16 + q * 4;
#pragma unroll
        for (int j = 0; j < 4; ++j) {
            int col = n0 + nw + j * 16 + lr;
#pragma unroll
            for (int reg = 0; reg < 4; ++reg) {
                float x = acc[i][j][reg];
                bf16_t hi = (bf16_t)x;
                bf16_t lo = (bf16_t)(x - (float)hi);
                int token = row + reg;
                if (col < 256) {
                    size_t o = (size_t)token * 256 + col;
                    Qhi[o] = hi;
                    Qlo[o] = lo;
                } else {
                    int hc = col - 256;
                    int h = hc >> 6, d = hc & 63;
                    int b = token >> 11, s = token & 2047;
                    int it2 = s >> 6, sl = s & 63;
                    size_t o = ((size_t)((b * 4 + h) * 32 + it2)) * 4096 +
                               (size_t)((d >> 3) * 64 + sl) * 8 + (d & 7);
                    Kbh[o] = hi;
                    Kbl[o] = lo;
                }
            }
        }
    }
}

// ---------------- flash attention, bf16 MFMA, dbuf coalesced staging ----------------
// grid 256 = b(2) x h(4) x qtile(32 of 64 rows); block 256 (4 waves x 16 q-rows).
__global__ __launch_bounds__(256, 1) void attn_mfma(const bf16_t* __restrict__ Qhi,
                                                    const bf16_t* __restrict__ Qlo,
                                                    const bf16_t* __restrict__ Kbh,
                                                    const bf16_t* __restrict__ Kbl,
                                                    const bf16_t* __restrict__ Vb,
                                                    const float* __restrict__ btab,
                                                    bf16_t* __restrict__ ctx) {
    __shared__ bf16_t Kh[2][4096], Kl[2][4096], Vsm[2][16384], Ps[4096];
    const int t = threadIdx.x, w = t >> 6, lane = t & 63;
    const int lr = lane & 15, q = lane >> 4;
    const int blk = blockIdx.x;
    const int qt = blk & 31, h = (blk >> 5) & 3, b = blk >> 7;
    const int n0 = qt * 64;
    const int rowbase = n0 + w * 16;  // within batch

    // Q fragments (hi/lo), registers: row = lr, k-chunk = kb*4+q
    const size_t qrow = (size_t)(b * 2048 + rowbase + lr) * 256 + h * 64;
    bf16x8 aqh[2], aql[2];
#pragma unroll
    for (int kb = 0; kb < 2; ++kb) {
        aqh[kb] = *(const bf16x8*)(Qhi + qrow + kb * 32 + q * 8);
        aql[kb] = *(const bf16x8*)(Qlo + qrow + kb * 32 + q * 8);
    }

    const bf16_t* gK = Kbh + ((size_t)((b * 4 + h) * 32)) * 4096;
    const bf16_t* gL = Kbl + ((size_t)((b * 4 + h) * 32)) * 4096;
    const bf16_t* gV = Vb + ((size_t)((b * 4 + h) * 32)) * 16384;
    const float* btabh = btab + h * 4608 + 2047;

    auto stage = [&](int bf, int it) {
        const bf16_t* k0 = gK + (size_t)it * 4096;
        gld16(k0 + t * 8, &Kh[bf][t * 8]);
        gld16(k0 + 2048 + t * 8, &Kh[bf][2048 + t * 8]);
        const bf16_t* l0 = gL + (size_t)it * 4096;
        gld16(l0 + t * 8, &Kl[bf][t * 8]);
        gld16(l0 + 2048 + t * 8, &Kl[bf][2048 + t * 8]);
        const bf16_t* v0 = gV + (size_t)it * 16384;
#pragma unroll
        for (int j = 0; j < 8; ++j)
            gld16(v0 + (j * 256 + t) * 8, &Vsm[bf][(j * 256 + t) * 8]);
    };

    float m_r[4], l_r[4];
#pragma unroll
    for (int reg = 0; reg < 4; ++reg) { m_r[reg] = -INFINITY; l_r[reg] = 0.f; }
    f32x4 O[16] = {};

    stage(0, 0);
    __syncthreads();
    for (int it = 0; it < 32; ++it) {
        const int cur = it & 1;
        if (it + 1 < 32) stage(cur ^ 1, it + 1);
        const int s0 = it * 64;

        // scores: S[16 rows][64 cols] per wave, hi/lo split
        f32x4 sc[4];
#pragma unroll
        for (int ct = 0; ct < 4; ++ct) {
            f32x4 z = {0.f, 0.f, 0.f, 0.f};
#pragma unroll
            for (int kb = 0; kb < 2; ++kb) {
                int sb = ((kb * 4 + q) * 64 + ct * 16 + lr) * 8;
                bf16x8 bh = *(const bf16x8*)&Kh[cur][sb];
                bf16x8 bl = *(const bf16x8*)&Kl[cur][sb];
                z = MFMA16(aqh[kb], bh, z);
                z = MFMA16(aqh[kb], bl, z);
                z = MFMA16(aql[kb], bh, z);
            }
            sc[ct] = z;
        }
        // bias: delta = (s0+ct*16+lr) - (rowbase+q*4+reg)
        const int dbase = (s0 + lr) - (rowbase + q * 4);
#pragma unroll
        for (int ct = 0; ct < 4; ++ct)
#pragma unroll
            for (int reg = 0; reg < 4; ++reg)
                sc[ct][reg] += btabh[dbase + ct * 16 - reg];

        // online softmax (rows wave-local; 16-lane col groups)
        float rm[4];
#pragma unroll
        for (int reg = 0; reg < 4; ++reg)
            rm[reg] = fmaxf(fmaxf(sc[0][reg], sc[1][reg]), fmaxf(sc[2][reg], sc[3][reg]));
#pragma unroll
        for (int off = 1; off < 16; off <<= 1)
#pragma unroll
            for (int reg = 0; reg < 4; ++reg)
                rm[reg] = fmaxf(rm[reg], __shfl_xor(rm[reg], off, 64));

        float alpha[4], rs[4];
#pragma unroll
        for (int reg = 0; reg < 4; ++reg) {
            float mo = m_r[reg];
            float mn = fmaxf(mo, rm[reg]);
            alpha[reg] = __expf(mo - mn);
            m_r[reg] = mn;
            rs[reg] = 0.f;
        }
#pragma unroll
        for (int ct = 0; ct < 4; ++ct) {
#pragma unroll
            for (int reg = 0; reg < 4; ++reg) {
                float p = __expf(sc[ct][reg] - m_r[reg]);
                rs[reg] += p;
                int col = ct * 16 + lr;
                Ps[((w * 128 + (col >> 3) * 16) + q * 4 + reg) * 8 + (col & 7)] = (bf16_t)p;
            }
        }
#pragma unroll
        for (int off = 1; off < 16; off <<= 1)
#pragma unroll
            for (int reg = 0; reg < 4; ++reg) rs[reg] += __shfl_xor(rs[reg], off, 64);
#pragma unroll
        for (int reg = 0; reg < 4; ++reg) l_r[reg] = l_r[reg] * alpha[reg] + rs[reg];

        // P A-fragments (wave-private LDS region)
        bf16x8 pa[2];
#pragma unroll
        for (int kb = 0; kb < 2; ++kb)
            pa[kb] = *(const bf16x8*)&Ps[(w * 128 + (kb * 4 + q) * 16 + lr) * 8];

        // O = alpha*O + P @ V
#pragma unroll
        for (int nt = 0; nt < 16; ++nt) {
            f32x4 o = O[nt];
#pragma unroll
            for (int reg = 0; reg < 4; ++reg) o[reg] *= alpha[reg];
#pragma unroll
            for (int kb = 0; kb < 2; ++kb) {
                bf16x8 v = *(const bf16x8*)&Vsm[cur][((kb * 4 + q) * 256 + nt * 16 + lr) * 8];
                o = MFMA16(pa[kb], v, o);
            }
            O[nt] = o;
        }
        __syncthreads();
    }

    // epilogue
    float inv[4];
#pragma unroll
    for (int reg = 0; reg < 4; ++reg) inv[reg] = 1.f / l_r[reg];
    const size_t tokbase = (size_t)(b * 2048 + rowbase + q * 4);
#pragma unroll
    for (int nt = 0; nt < 16; ++nt) {
        int v = nt * 16 + lr;
        int vg = ((v >> 6) * 4 + h) * 64 + (v & 63);
#pragma unroll
        for (int reg = 0; reg < 4; ++reg)
            ctx[(tokbase + reg) * 1024 + vg] = (bf16_t)(O[nt][reg] * inv[reg]);
    }
}

extern "C" void kernel_launch(void* const* d_in, const int* in_sizes, int n_in,
                              void* d_out, int out_size, void* d_ws, size_t ws_size,
                              hipStream_t stream) {
    const float* hs = (const float*)d_in[0];
    const float* Wq = (const float*)d_in[1];
    const float* Wk = (const float*)d_in[2];
    const float* Wv = (const float*)d_in[3];
    const float* Wo = (const float*)d_in[4];
    const float* rb = (const float*)d_in[5];
    float* out = (float*)d_out;

    char* ws = (char*)d_ws;
    bf16_t* hs_hi = (bf16_t*)(ws);                      // 8 MB; reused as ctx
    bf16_t* hs_lo = (bf16_t*)(ws + (8 << 20));          // 8 MB; reused as Vb
    bf16_t* WqkThi = (bf16_t*)(ws + (16 << 20));        // 1 MB
    bf16_t* WqkTlo = (bf16_t*)(ws + (17 << 20));        // 1 MB
    bf16_t* WvT = (bf16_t*)(ws + (18 << 20));           // 2 MB
    bf16_t* WoT = (bf16_t*)(ws + (20 << 20));           // 2 MB
    float* btab = (float*)(ws + (22 << 20));            // 4*4608*4 B = 72 KB (pad 128K)
    bf16_t* Qhi = (bf16_t*)(ws + (22 << 20) + 131072);  // 2 MB
    bf16_t* Qlo = Qhi + (size_t)4096 * 256;             // 2 MB
    bf16_t* Kbh = Qlo + (size_t)4096 * 256;             // 2 MB (256 tiles x 8KB)
    bf16_t* Kbl = Kbh + (size_t)4096 * 256;             // 2 MB
    bf16_t* Vb = hs_lo;   // alias: hs_lo dead after gemm_qk
    bf16_t* ctx = hs_hi;  // alias: hs_hi dead after V GEMM

    cast_hs<<<4096, 256, 0, stream>>>(hs, hs_hi, hs_lo);
    prep_wqk<<<1024, 256, 0, stream>>>(Wq, Wk, WqkThi, WqkTlo);
    transpose_to_bf16<<<dim3(32, 32), 256, 0, stream>>>(Wv, WvT);
    transpose_to_bf16<<<dim3(32, 32), 256, 0, stream>>>(Wo, WoT);
    prep_bias<<<16, 256, 0, stream>>>(rb, btab);

    // QK projection (hi/lo): Q rows + K blocked
    gemm_qk<<<dim3(4, 32), 256, 0, stream>>>(hs_hi, hs_lo, WqkThi, WqkTlo, Qhi, Qlo, Kbh,
                                             Kbl, 1024);
    // V blocked: [1024 vg][4096 tok] = WvT * hs^T, scattered to per-(b,h,it) tiles
    gemm_mfma<2><<<dim3(32, 8), 256, 0, stream>>>(WvT, hs_hi, Vb, 1024, 4096, 1024);
    // attention -> ctx bf16 [4096][1024]
    attn_mfma<<<256, 256, 0, stream>>>(Qhi, Qlo, Kbh, Kbl, Vb, btab, ctx);
    // out = ctx * WoT^T (fp32 out)
    gemm_mfma<0><<<dim3(8, 32), 256, 0, stream>>>(ctx, WoT, out, 4096, 1024, 1024);
}

// Round 4
// 286.549 us; speedup vs baseline: 4.6073x; 1.0927x over previous
//
#include <hip/hip_runtime.h>
#include <math.h>

// B=2, S=2048, D_MODEL=1024, D_KV=64, N_HEADS=16, KV_HEADS=4, G=4
// Pipeline (bf16 MFMA, fp32 accumulate):
//   cast hs -> hi/lo bf16; Wq(sum_g)/Wk(mean_g) -> WqkT hi/lo [512][1024]
//   gemm_qk -> Q hi/lo [4096][256] row-major + K hi/lo in BLOCKED per-(b,h,it) tiles
//   V GEMM  -> V in BLOCKED per-(b,h,it) tiles (LDS slot order, coalesced staging)
//   attn: 512-thread blocks, split-s x2 (grid 256, 8 waves/CU), dbuf LDS staging,
//         MFMA QK^T/PV + online softmax -> per-half normalized partials + m+log(l)
//   combine: merge halves elementwise (in-place) -> ctx bf16
//   out = ctx @ Wo (bf16 MFMA, fp32 out)

typedef __bf16 bf16_t;
typedef bf16_t bf16x8 __attribute__((ext_vector_type(8)));
typedef bf16_t bf16x4 __attribute__((ext_vector_type(4)));
typedef float f32x4 __attribute__((ext_vector_type(4)));

#define MFMA16(a, b, c) __builtin_amdgcn_mfma_f32_16x16x32_bf16(a, b, c, 0, 0, 0)

typedef __attribute__((address_space(1))) void gvoid;
typedef __attribute__((address_space(3))) void svoid;
__device__ __forceinline__ void gld16(const void* g, void* l) {
    __builtin_amdgcn_global_load_lds((gvoid*)g, (svoid*)l, 16, 0, 0);
}

// ---------------- prep: cast hs to hi/lo bf16 ----------------
__global__ __launch_bounds__(256) void cast_hs(const float* __restrict__ x,
                                               bf16_t* __restrict__ hi,
                                               bf16_t* __restrict__ lo) {
    size_t idx = ((size_t)blockIdx.x * 256 + threadIdx.x) * 4;
    float4 v = *(const float4*)(x + idx);
    bf16x4 h, l;
    h[0] = (bf16_t)v.x; l[0] = (bf16_t)(v.x - (float)h[0]);
    h[1] = (bf16_t)v.y; l[1] = (bf16_t)(v.y - (float)h[1]);
    h[2] = (bf16_t)v.z; l[2] = (bf16_t)(v.z - (float)h[2]);
    h[3] = (bf16_t)v.w; l[3] = (bf16_t)(v.w - (float)h[3]);
    *(bf16x4*)(hi + idx) = h;
    *(bf16x4*)(lo + idx) = l;
}

// ---------------- prep: reduced QK weights, transposed, hi/lo ----------------
__global__ __launch_bounds__(256) void prep_wqk(const float* __restrict__ Wq,
                                                const float* __restrict__ Wk,
                                                bf16_t* __restrict__ Thi,
                                                bf16_t* __restrict__ Tlo) {
    __shared__ float rq[1024], rk[1024];
    int k = blockIdx.x, t = threadIdx.x;
#pragma unroll
    for (int j = 0; j < 4; ++j) {
        rq[t + j * 256] = Wq[(size_t)k * 1024 + t + j * 256];
        rk[t + j * 256] = Wk[(size_t)k * 1024 + t + j * 256];
    }
    __syncthreads();
    int h = t >> 6, j2 = t & 63;
    float sq = 0.f, sk = 0.f;
#pragma unroll
    for (int g = 0; g < 4; ++g) {
        sq += rq[(g * 4 + h) * 64 + j2];
        sk += rk[(g * 4 + h) * 64 + j2];
    }
    sk *= 0.25f;
    bf16_t qh = (bf16_t)sq;
    Thi[(size_t)t * 1024 + k] = qh;
    Tlo[(size_t)t * 1024 + k] = (bf16_t)(sq - (float)qh);
    bf16_t kh = (bf16_t)sk;
    Thi[(size_t)(256 + t) * 1024 + k] = kh;
    Tlo[(size_t)(256 + t) * 1024 + k] = (bf16_t)(sk - (float)kh);
}

// ---------------- prep: transpose 1024x1024 f32 -> bf16 ----------------
__global__ __launch_bounds__(256) void transpose_to_bf16(const float* __restrict__ src,
                                                         bf16_t* __restrict__ dst) {
    __shared__ float tile[32][33];
    int tx = threadIdx.x & 31, ty = threadIdx.x >> 5;
    int bx = blockIdx.x * 32, by = blockIdx.y * 32;
#pragma unroll
    for (int i = 0; i < 32; i += 8)
        tile[ty + i][tx] = src[(size_t)(by + ty + i) * 1024 + bx + tx];
    __syncthreads();
#pragma unroll
    for (int i = 0; i < 32; i += 8)
        dst[(size_t)(bx + ty + i) * 1024 + by + tx] = (bf16_t)tile[tx][ty + i];
}

// ---------------- prep: bias table, layout [4 heads][4608] ----------------
__global__ __launch_bounds__(256) void prep_bias(const float* __restrict__ rel_bias,
                                                 float* __restrict__ table) {
    int idx = blockIdx.x * 256 + threadIdx.x;
    if (idx >= 4095) return;
    int delta = idx - 2047;  // mem - ctx
    int bucket = (delta > 0) ? 16 : 0;
    int arp = delta < 0 ? -delta : delta;
    int rb;
    if (arp < 8) {
        rb = arp;
    } else {
        float tt = (logf((float)arp * 0.125f) / 2.772588722239781f) * 8.0f;
        int ri = 8 + (int)tt;
        rb = ri < 15 ? ri : 15;
    }
    bucket += rb;
#pragma unroll
    for (int h = 0; h < 4; ++h) {
        float s = 0.25f * (rel_bias[bucket * 16 + h] + rel_bias[bucket * 16 + h + 4] +
                           rel_bias[bucket * 16 + h + 8] + rel_bias[bucket * 16 + h + 12]);
        table[h * 4608 + idx] = s;
    }
}

// ---------------- bf16 MFMA GEMM: C[M,N] = A[M,K] * BT[N,K]^T ----------------
// MODE 0: f32 row-major out. MODE 2: bf16 V-blocked out (per-(b,h,it) 32KB tiles,
//         slot = schunk*256 + g*64 + d, 8 tokens per slot).
template <int MODE>
__global__ __launch_bounds__(256, 1) void gemm_mfma(const bf16_t* __restrict__ A,
                                                    const bf16_t* __restrict__ BT,
                                                    void* __restrict__ Cv,
                                                    int M, int N, int K) {
    __shared__ bf16_t As[2][4096];
    __shared__ bf16_t Bs[2][4096];
    const int t = threadIdx.x;
    const int w = t >> 6, lane = t & 63;
    const int lr = lane & 15, q = lane >> 4;
    const int m0 = blockIdx.y * 128, n0 = blockIdx.x * 128;
    const int mw = (w & 1) * 64, nw = (w >> 1) * 64;
    f32x4 acc[4][4] = {};
    const int nk = K >> 5;

    const int s0i = t, s1i = 256 + t;
    const int c0 = s0i >> 7, r0 = s0i & 127;
    const int c1 = s1i >> 7, r1 = s1i & 127;
    const bf16_t* gA0 = A + (size_t)(m0 + r0) * K + c0 * 8;
    const bf16_t* gA1 = A + (size_t)(m0 + r1) * K + c1 * 8;
    const bf16_t* gB0 = BT + (size_t)(n0 + r0) * K + c0 * 8;
    const bf16_t* gB1 = BT + (size_t)(n0 + r1) * K + c1 * 8;
    const int ldsA = (w * 64) * 8, ldsB = (256 + w * 64) * 8;

    auto stage = [&](int bf, int k0) {
        gld16(gA0 + k0, &As[bf][ldsA]);
        gld16(gA1 + k0, &As[bf][ldsB]);
        gld16(gB0 + k0, &Bs[bf][ldsA]);
        gld16(gB1 + k0, &Bs[bf][ldsB]);
    };

    stage(0, 0);
    __syncthreads();
    for (int it = 0; it < nk; ++it) {
        const int cur = it & 1;
        if (it + 1 < nk) stage(cur ^ 1, (it + 1) * 32);
        bf16x8 af[4], bfv[4];
#pragma unroll
        for (int i = 0; i < 4; ++i)
            af[i] = *(const bf16x8*)&As[cur][(q * 128 + mw + i * 16 + lr) * 8];
#pragma unroll
        for (int j = 0; j < 4; ++j)
            bfv[j] = *(const bf16x8*)&Bs[cur][(q * 128 + nw + j * 16 + lr) * 8];
#pragma unroll
        for (int i = 0; i < 4; ++i)
#pragma unroll
            for (int j = 0; j < 4; ++j) acc[i][j] = MFMA16(af[i], bfv[j], acc[i][j]);
        __syncthreads();
    }

#pragma unroll
    for (int i = 0; i < 4; ++i) {
        int row = m0 + mw + i * 16 + q * 4;
#pragma unroll
        for (int j = 0; j < 4; ++j) {
            int col = n0 + nw + j * 16 + lr;
#pragma unroll
            for (int reg = 0; reg < 4; ++reg) {
                if (MODE == 0) {
                    ((float*)Cv)[(size_t)(row + reg) * N + col] = acc[i][j][reg];
                } else {
                    // row = vg (0..1023), col = token (0..4095)
                    int vg = row + reg;
                    int hd = vg >> 6, d = vg & 63;
                    int h = hd & 3, g = hd >> 2;
                    int b = col >> 11, s = col & 2047;
                    int it2 = s >> 6, sc = (s >> 3) & 7, si = s & 7;
                    size_t o = ((size_t)((b * 4 + h) * 32 + it2)) * 16384 +
                               (size_t)(sc * 256 + g * 64 + d) * 8 + si;
                    ((bf16_t*)Cv)[o] = (bf16_t)acc[i][j][reg];
                }
            }
        }
    }
}

// ---------------- hi/lo split GEMM for QK projection ----------------
__global__ __launch_bounds__(256, 1) void gemm_qk(const bf16_t* __restrict__ Ah,
                                                  const bf16_t* __restrict__ Al,
                                                  const bf16_t* __restrict__ Bh,
                                                  const bf16_t* __restrict__ Bl,
                                                  bf16_t* __restrict__ Qhi,
                                                  bf16_t* __restrict__ Qlo,
                                                  bf16_t* __restrict__ Kbh,
                                                  bf16_t* __restrict__ Kbl,
                                                  int K) {
    __shared__ bf16_t AsH[2][4096], AsL[2][4096], BsH[2][4096], BsL[2][4096];
    const int t = threadIdx.x;
    const int w = t >> 6, lane = t & 63;
    const int lr = lane & 15, q = lane >> 4;
    const int m0 = blockIdx.y * 128, n0 = blockIdx.x * 128;
    const int mw = (w & 1) * 64, nw = (w >> 1) * 64;
    f32x4 acc[4][4] = {};
    const int nk = K >> 5;

    const int s0i = t, s1i = 256 + t;
    const int c0 = s0i >> 7, r0 = s0i & 127;
    const int c1 = s1i >> 7, r1 = s1i & 127;
    const size_t oA0 = (size_t)(m0 + r0) * K + c0 * 8;
    const size_t oA1 = (size_t)(m0 + r1) * K + c1 * 8;
    const size_t oB0 = (size_t)(n0 + r0) * K + c0 * 8;
    const size_t oB1 = (size_t)(n0 + r1) * K + c1 * 8;
    const int ldsA = (w * 64) * 8, ldsB = (256 + w * 64) * 8;

    auto stage = [&](int bf, int k0) {
        gld16(Ah + oA0 + k0, &AsH[bf][ldsA]);
        gld16(Ah + oA1 + k0, &AsH[bf][ldsB]);
        gld16(Al + oA0 + k0, &AsL[bf][ldsA]);
        gld16(Al + oA1 + k0, &AsL[bf][ldsB]);
        gld16(Bh + oB0 + k0, &BsH[bf][ldsA]);
        gld16(Bh + oB1 + k0, &BsH[bf][ldsB]);
        gld16(Bl + oB0 + k0, &BsL[bf][ldsA]);
        gld16(Bl + oB1 + k0, &BsL[bf][ldsB]);
    };

    stage(0, 0);
    __syncthreads();
    for (int it = 0; it < nk; ++it) {
        const int cur = it & 1;
        if (it + 1 < nk) stage(cur ^ 1, (it + 1) * 32);
        bf16x8 ah[4], al[4], bh[4], bl[4];
#pragma unroll
        for (int i = 0; i < 4; ++i) {
            int sa = (q * 128 + mw + i * 16 + lr) * 8;
            ah[i] = *(const bf16x8*)&AsH[cur][sa];
            al[i] = *(const bf16x8*)&AsL[cur][sa];
        }
#pragma unroll
        for (int j = 0; j < 4; ++j) {
            int sb = (q * 128 + nw + j * 16 + lr) * 8;
            bh[j] = *(const bf16x8*)&BsH[cur][sb];
            bl[j] = *(const bf16x8*)&BsL[cur][sb];
        }
#pragma unroll
        for (int i = 0; i < 4; ++i)
#pragma unroll
            for (int j = 0; j < 4; ++j) {
                acc[i][j] = MFMA16(ah[i], bh[j], acc[i][j]);
                acc[i][j] = MFMA16(ah[i], bl[j], acc[i][j]);
                acc[i][j] = MFMA16(al[i], bh[j], acc[i][j]);
            }
        __syncthreads();
    }

#pragma unroll
    for (int i = 0; i < 4; ++i) {
        int row = m0 + mw + i * 16 + q * 4;
#pragma unroll
        for (int j = 0; j < 4; ++j) {
            int col = n0 + nw + j * 16 + lr;
#pragma unroll
            for (int reg = 0; reg < 4; ++reg) {
                float x = acc[i][j][reg];
                bf16_t hi = (bf16_t)x;
                bf16_t lo = (bf16_t)(x - (float)hi);
                int token = row + reg;
                if (col < 256) {
                    size_t o = (size_t)token * 256 + col;
                    Qhi[o] = hi;
                    Qlo[o] = lo;
                } else {
                    int hc = col - 256;
                    int h = hc >> 6, d = hc & 63;
                    int b = token >> 11, s = token & 2047;
                    int it2 = s >> 6, sl = s & 63;
                    size_t o = ((size_t)((b * 4 + h) * 32 + it2)) * 4096 +
                               (size_t)((d >> 3) * 64 + sl) * 8 + (d & 7);
                    Kbh[o] = hi;
                    Kbl[o] = lo;
                }
            }
        }
    }
}

// ---------------- flash attention, 512 threads, split-s x2 ----------------
// grid 256 = b(2) x h(4) x qtile(16 of 128 rows) x shalf(2); 8 waves x 16 q-rows.
// Writes normalized partial O (bf16, ctx layout) + Sml = m + log(l) per row.
__global__ __launch_bounds__(512, 1) void attn_mfma(const bf16_t* __restrict__ Qhi,
                                                    const bf16_t* __restrict__ Qlo,
                                                    const bf16_t* __restrict__ Kbh,
                                                    const bf16_t* __restrict__ Kbl,
                                                    const bf16_t* __restrict__ Vb,
                                                    const float* __restrict__ btab,
                                                    bf16_t* __restrict__ part0,
                                                    bf16_t* __restrict__ part1,
                                                    float* __restrict__ Sml) {
    __shared__ bf16_t Kh[2][4096], Kl[2][4096], Vsm[2][16384], Ps[8192];
    const int t = threadIdx.x, w = t >> 6, lane = t & 63;
    const int lr = lane & 15, q = lane >> 4;
    const int blk = blockIdx.x;
    const int half = blk & 1, qt = (blk >> 1) & 15, h = (blk >> 5) & 3, b = blk >> 7;
    const int n0 = qt * 128;
    const int rowbase = n0 + w * 16;  // within batch

    // Q fragments (hi/lo), registers: row = lr, k-chunk = kb*4+q
    const size_t qrow = (size_t)(b * 2048 + rowbase + lr) * 256 + h * 64;
    bf16x8 aqh[2], aql[2];
#pragma unroll
    for (int kb = 0; kb < 2; ++kb) {
        aqh[kb] = *(const bf16x8*)(Qhi + qrow + kb * 32 + q * 8);
        aql[kb] = *(const bf16x8*)(Qlo + qrow + kb * 32 + q * 8);
    }

    const int tilebase = (b * 4 + h) * 32 + half * 16;
    const bf16_t* gK = Kbh + (size_t)tilebase * 4096;
    const bf16_t* gL = Kbl + (size_t)tilebase * 4096;
    const bf16_t* gV = Vb + (size_t)tilebase * 16384;
    const float* btabh = btab + h * 4608 + 2047;

    auto stage = [&](int bf, int it) {
        gld16(gK + (size_t)it * 4096 + t * 8, &Kh[bf][t * 8]);
        gld16(gL + (size_t)it * 4096 + t * 8, &Kl[bf][t * 8]);
        const bf16_t* v0 = gV + (size_t)it * 16384;
#pragma unroll
        for (int j = 0; j < 4; ++j)
            gld16(v0 + (j * 512 + t) * 8, &Vsm[bf][(j * 512 + t) * 8]);
    };

    float m_r[4], l_r[4];
#pragma unroll
    for (int reg = 0; reg < 4; ++reg) { m_r[reg] = -INFINITY; l_r[reg] = 0.f; }
    f32x4 O[16] = {};

    stage(0, 0);
    __syncthreads();
    for (int it = 0; it < 16; ++it) {
        const int cur = it & 1;
        if (it + 1 < 16) stage(cur ^ 1, it + 1);
        const int s0g = half * 1024 + it * 64;

        // scores: S[16 rows][64 cols] per wave, hi/lo split
        f32x4 sc[4];
#pragma unroll
        for (int ct = 0; ct < 4; ++ct) {
            f32x4 z = {0.f, 0.f, 0.f, 0.f};
#pragma unroll
            for (int kb = 0; kb < 2; ++kb) {
                int sb = ((kb * 4 + q) * 64 + ct * 16 + lr) * 8;
                bf16x8 bh = *(const bf16x8*)&Kh[cur][sb];
                bf16x8 bl = *(const bf16x8*)&Kl[cur][sb];
                z = MFMA16(aqh[kb], bh, z);
                z = MFMA16(aqh[kb], bl, z);
                z = MFMA16(aql[kb], bh, z);
            }
            sc[ct] = z;
        }
        // bias: delta = (s0g+ct*16+lr) - (rowbase+q*4+reg)
        const int dbase = (s0g + lr) - (rowbase + q * 4);
#pragma unroll
        for (int ct = 0; ct < 4; ++ct)
#pragma unroll
            for (int reg = 0; reg < 4; ++reg)
                sc[ct][reg] += btabh[dbase + ct * 16 - reg];

        // online softmax (rows wave-local; 16-lane col groups)
        float rm[4];
#pragma unroll
        for (int reg = 0; reg < 4; ++reg)
            rm[reg] = fmaxf(fmaxf(sc[0][reg], sc[1][reg]), fmaxf(sc[2][reg], sc[3][reg]));
#pragma unroll
        for (int off = 1; off < 16; off <<= 1)
#pragma unroll
            for (int reg = 0; reg < 4; ++reg)
                rm[reg] = fmaxf(rm[reg], __shfl_xor(rm[reg], off, 64));

        float alpha[4], rs[4];
#pragma unroll
        for (int reg = 0; reg < 4; ++reg) {
            float mo = m_r[reg];
            float mn = fmaxf(mo, rm[reg]);
            alpha[reg] = __expf(mo - mn);
            m_r[reg] = mn;
            rs[reg] = 0.f;
        }
#pragma unroll
        for (int ct = 0; ct < 4; ++ct) {
#pragma unroll
            for (int reg = 0; reg < 4; ++reg) {
                float p = __expf(sc[ct][reg] - m_r[reg]);
                rs[reg] += p;
                int col = ct * 16 + lr;
                Ps[((w * 128 + (col >> 3) * 16) + q * 4 + reg) * 8 + (col & 7)] = (bf16_t)p;
            }
        }
#pragma unroll
        for (int off = 1; off < 16; off <<= 1)
#pragma unroll
            for (int reg = 0; reg < 4; ++reg) rs[reg] += __shfl_xor(rs[reg], off, 64);
#pragma unroll
        for (int reg = 0; reg < 4; ++reg) l_r[reg] = l_r[reg] * alpha[reg] + rs[reg];

        // P A-fragments (wave-private LDS region)
        bf16x8 pa[2];
#pragma unroll
        for (int kb = 0; kb < 2; ++kb)
            pa[kb] = *(const bf16x8*)&Ps[(w * 128 + (kb * 4 + q) * 16 + lr) * 8];

        // O = alpha*O + P @ V
#pragma unroll
        for (int nt = 0; nt < 16; ++nt) {
            f32x4 o = O[nt];
#pragma unroll
            for (int reg = 0; reg < 4; ++reg) o[reg] *= alpha[reg];
#pragma unroll
            for (int kb = 0; kb < 2; ++kb) {
                bf16x8 v = *(const bf16x8*)&Vsm[cur][((kb * 4 + q) * 256 + nt * 16 + lr) * 8];
                o = MFMA16(pa[kb], v, o);
            }
            O[nt] = o;
        }
        __syncthreads();
    }

    // epilogue: normalized partial O + per-row m+log(l)
    bf16_t* P = half ? part1 : part0;
    float inv[4];
#pragma unroll
    for (int reg = 0; reg < 4; ++reg) inv[reg] = 1.f / l_r[reg];
    const size_t tokbase = (size_t)(b * 2048 + rowbase + q * 4);
#pragma unroll
    for (int nt = 0; nt < 16; ++nt) {
        int v = nt * 16 + lr;
        int vg = ((v >> 6) * 4 + h) * 64 + (v & 63);
#pragma unroll
        for (int reg = 0; reg < 4; ++reg)
            P[(tokbase + reg) * 1024 + vg] = (bf16_t)(O[nt][reg] * inv[reg]);
    }
    if (lr == 0) {
#pragma unroll
        for (int reg = 0; reg < 4; ++reg)
            Sml[half * 16384 + (tokbase + reg) * 4 + h] = m_r[reg] + logf(l_r[reg]);
    }
}

// ---------------- combine the two s-halves (in-place into part0) ----------------
__global__ __launch_bounds__(256) void combine_halves(bf16_t* __restrict__ p0,
                                                      const bf16_t* __restrict__ p1,
                                                      const float* __restrict__ Sml) {
    size_t flat = ((size_t)blockIdx.x * 256 + threadIdx.x) * 8;
    int tok = (int)(flat >> 10), c = (int)(flat & 1023), h = (c >> 6) & 3;
    float s0 = Sml[tok * 4 + h], s1 = Sml[16384 + tok * 4 + h];
    float M = fmaxf(s0, s1);
    float e0 = __expf(s0 - M), e1 = __expf(s1 - M);
    float r = 1.f / (e0 + e1);
    float w0 = e0 * r, w1 = e1 * r;
    bf16x8 a = *(bf16x8*)(p0 + flat);
    bf16x8 bb = *(const bf16x8*)(p1 + flat);
    bf16x8 o;
#pragma unroll
    for (int i = 0; i < 8; ++i) o[i] = (bf16_t)(w0 * (float)a[i] + w1 * (float)bb[i]);
    *(bf16x8*)(p0 + flat) = o;
}

extern "C" void kernel_launch(void* const* d_in, const int* in_sizes, int n_in,
                              void* d_out, int out_size, void* d_ws, size_t ws_size,
                              hipStream_t stream) {
    const float* hs = (const float*)d_in[0];
    const float* Wq = (const float*)d_in[1];
    const float* Wk = (const float*)d_in[2];
    const float* Wv = (const float*)d_in[3];
    const float* Wo = (const float*)d_in[4];
    const float* rb = (const float*)d_in[5];
    float* out = (float*)d_out;

    const size_t MB = 1 << 20;
    char* ws = (char*)d_ws;
    // lifetimes: hs_hi(0-8) dies after V gemm -> part0 -> ctx (in-place combine)
    //            hs_lo(8-16) dies after gemm_qk -> Vb
    //            16-24: WqkThi(16-18)/WqkTlo(18-20)/WvT(20-22) die before attn -> part1
    bf16_t* hs_hi = (bf16_t*)(ws);
    bf16_t* hs_lo = (bf16_t*)(ws + 8 * MB);
    bf16_t* part1 = (bf16_t*)(ws + 16 * MB);
    bf16_t* WqkThi = (bf16_t*)(ws + 16 * MB);
    bf16_t* WqkTlo = (bf16_t*)(ws + 18 * MB);
    bf16_t* WvT = (bf16_t*)(ws + 20 * MB);
    bf16_t* WoT = (bf16_t*)(ws + 24 * MB);           // live to end
    float* btab = (float*)(ws + 26 * MB);            // 72 KB (pad 128K)
    float* Sml = (float*)(ws + 26 * MB + 131072);    // 128 KB
    bf16_t* Qhi = (bf16_t*)(ws + 26 * MB + 262144);  // 2 MB
    bf16_t* Qlo = Qhi + (size_t)4096 * 256;          // 2 MB
    bf16_t* Kbh = Qlo + (size_t)4096 * 256;          // 2 MB
    bf16_t* Kbl = Kbh + (size_t)4096 * 256;          // 2 MB (ends ~34.25 MB)
    bf16_t* Vb = hs_lo;
    bf16_t* part0 = hs_hi;  // partial half-0, then ctx in-place

    cast_hs<<<4096, 256, 0, stream>>>(hs, hs_hi, hs_lo);
    prep_wqk<<<1024, 256, 0, stream>>>(Wq, Wk, WqkThi, WqkTlo);
    transpose_to_bf16<<<dim3(32, 32), 256, 0, stream>>>(Wv, WvT);
    transpose_to_bf16<<<dim3(32, 32), 256, 0, stream>>>(Wo, WoT);
    prep_bias<<<16, 256, 0, stream>>>(rb, btab);

    // QK projection (hi/lo): Q rows + K blocked
    gemm_qk<<<dim3(4, 32), 256, 0, stream>>>(hs_hi, hs_lo, WqkThi, WqkTlo, Qhi, Qlo, Kbh,
                                             Kbl, 1024);
    // V blocked: [1024 vg][4096 tok] = WvT * hs^T, scattered to per-(b,h,it) tiles
    gemm_mfma<2><<<dim3(32, 8), 256, 0, stream>>>(WvT, hs_hi, Vb, 1024, 4096, 1024);
    // attention -> partial halves + Sml
    attn_mfma<<<256, 512, 0, stream>>>(Qhi, Qlo, Kbh, Kbl, Vb, btab, part0, part1, Sml);
    // merge halves -> ctx (in-place in part0)
    combine_halves<<<2048, 256, 0, stream>>>(part0, part1, Sml);
    // out = ctx * WoT^T (fp32 out)
    gemm_mfma<0><<<dim3(8, 32), 256, 0, stream>>>(part0, WoT, out, 4096, 1024, 1024);
}

// Round 7
// 262.906 us; speedup vs baseline: 5.0217x; 1.0899x over previous
//
#include <hip/hip_runtime.h>
#include <math.h>

// B=2, S=2048, D_MODEL=1024, D_KV=64, N_HEADS=16, KV_HEADS=4, G=4
// Pipeline (bf16 MFMA, fp32 accumulate):
//   prep_all: cast hs hi/lo; WqkT hi/lo; WvT/WoT bf16; bias table   (1 launch)
//   proj_qkv: Q hi/lo rows + K hi/lo blocked + V blocked            (1 launch, 384 blk)
//     NOTE: Vb MUST NOT alias hs_lo — QK blocks read hs_lo while V blocks write Vb
//     in the SAME launch (this race was the R5/R6 failure).
//   attn: 512-thr blocks, split-s x2, online softmax (R4-verified loop),
//         normalized partial O + m+log(l)
//   combine: softmax-weighted merge of halves -> ctx bf16
//   out = ctx @ Wo (fp32 out)

typedef __bf16 bf16_t;
typedef bf16_t bf16x8 __attribute__((ext_vector_type(8)));
typedef bf16_t bf16x4 __attribute__((ext_vector_type(4)));
typedef float f32x4 __attribute__((ext_vector_type(4)));

#define MFMA16(a, b, c) __builtin_amdgcn_mfma_f32_16x16x32_bf16(a, b, c, 0, 0, 0)

typedef __attribute__((address_space(1))) void gvoid;
typedef __attribute__((address_space(3))) void svoid;
__device__ __forceinline__ void gld16(const void* g, void* l) {
    __builtin_amdgcn_global_load_lds((gvoid*)g, (svoid*)l, 16, 0, 0);
}

// ---------------- prep_all: fused block-range dispatch ----------------
// [0,4096): cast hs -> hi/lo       [4096,5120): reduced WqkT hi/lo
// [5120,6144): WvT transpose       [6144,7168): WoT transpose
// [7168,7184): bias table
__global__ __launch_bounds__(256) void prep_all(const float* __restrict__ hs,
                                                const float* __restrict__ Wq,
                                                const float* __restrict__ Wk,
                                                const float* __restrict__ Wv,
                                                const float* __restrict__ Wo,
                                                const float* __restrict__ rel_bias,
                                                bf16_t* __restrict__ hs_hi,
                                                bf16_t* __restrict__ hs_lo,
                                                bf16_t* __restrict__ Thi,
                                                bf16_t* __restrict__ Tlo,
                                                bf16_t* __restrict__ WvT,
                                                bf16_t* __restrict__ WoT,
                                                float* __restrict__ btab) {
    __shared__ float sm[2048];
    const int r = blockIdx.x, t = threadIdx.x;
    if (r < 4096) {
        size_t idx = ((size_t)r * 256 + t) * 4;
        float4 v = *(const float4*)(hs + idx);
        bf16x4 h, l;
        h[0] = (bf16_t)v.x; l[0] = (bf16_t)(v.x - (float)h[0]);
        h[1] = (bf16_t)v.y; l[1] = (bf16_t)(v.y - (float)h[1]);
        h[2] = (bf16_t)v.z; l[2] = (bf16_t)(v.z - (float)h[2]);
        h[3] = (bf16_t)v.w; l[3] = (bf16_t)(v.w - (float)h[3]);
        *(bf16x4*)(hs_hi + idx) = h;
        *(bf16x4*)(hs_lo + idx) = l;
    } else if (r < 5120) {
        int k = r - 4096;
        float* rq = sm;
        float* rk = sm + 1024;
#pragma unroll
        for (int j = 0; j < 4; ++j) {
            rq[t + j * 256] = Wq[(size_t)k * 1024 + t + j * 256];
            rk[t + j * 256] = Wk[(size_t)k * 1024 + t + j * 256];
        }
        __syncthreads();
        int h = t >> 6, j2 = t & 63;
        float sq = 0.f, sk = 0.f;
#pragma unroll
        for (int g = 0; g < 4; ++g) {
            sq += rq[(g * 4 + h) * 64 + j2];
            sk += rk[(g * 4 + h) * 64 + j2];
        }
        sk *= 0.25f;
        bf16_t qh = (bf16_t)sq;
        Thi[(size_t)t * 1024 + k] = qh;
        Tlo[(size_t)t * 1024 + k] = (bf16_t)(sq - (float)qh);
        bf16_t kh = (bf16_t)sk;
        Thi[(size_t)(256 + t) * 1024 + k] = kh;
        Tlo[(size_t)(256 + t) * 1024 + k] = (bf16_t)(sk - (float)kh);
    } else if (r < 7168) {
        const float* src = (r < 6144) ? Wv : Wo;
        bf16_t* dst = (r < 6144) ? WvT : WoT;
        int rr = (r < 6144) ? r - 5120 : r - 6144;
        int bx = (rr & 31) * 32, by = (rr >> 5) * 32;
        int tx = t & 31, ty = t >> 5;
        float(*tile)[33] = (float(*)[33])sm;  // 32x33 = 1056 floats
#pragma unroll
        for (int i = 0; i < 32; i += 8)
            tile[ty + i][tx] = src[(size_t)(by + ty + i) * 1024 + bx + tx];
        __syncthreads();
#pragma unroll
        for (int i = 0; i < 32; i += 8)
            dst[(size_t)(bx + ty + i) * 1024 + by + tx] = (bf16_t)tile[tx][ty + i];
    } else {
        int idx = (r - 7168) * 256 + t;
        if (idx >= 4095) return;
        int delta = idx - 2047;
        int bucket = (delta > 0) ? 16 : 0;
        int arp = delta < 0 ? -delta : delta;
        int rb;
        if (arp < 8) {
            rb = arp;
        } else {
            float tt = (logf((float)arp * 0.125f) / 2.772588722239781f) * 8.0f;
            int ri = 8 + (int)tt;
            rb = ri < 15 ? ri : 15;
        }
        bucket += rb;
#pragma unroll
        for (int h = 0; h < 4; ++h) {
            float s = 0.25f * (rel_bias[bucket * 16 + h] + rel_bias[bucket * 16 + h + 4] +
                               rel_bias[bucket * 16 + h + 8] + rel_bias[bucket * 16 + h + 12]);
            btab[h * 4608 + idx] = s;
        }
    }
}

// ---------------- fused projection GEMM ----------------
// blockIdx.x < 4: QK cols (hi/lo split, 3 MFMAs) -> Q rows + K blocked
// blockIdx.x >= 4: V cols (plain bf16)          -> V blocked
__global__ __launch_bounds__(256, 1) void proj_qkv(const bf16_t* __restrict__ Ah,
                                                   const bf16_t* __restrict__ Al,
                                                   const bf16_t* __restrict__ Bh,
                                                   const bf16_t* __restrict__ Bl,
                                                   const bf16_t* __restrict__ WvT,
                                                   bf16_t* __restrict__ Qhi,
                                                   bf16_t* __restrict__ Qlo,
                                                   bf16_t* __restrict__ Kbh,
                                                   bf16_t* __restrict__ Kbl,
                                                   bf16_t* __restrict__ Vb) {
    __shared__ bf16_t AsH[2][4096], AsL[2][4096], BsH[2][4096], BsL[2][4096];
    const int K = 1024, nk = 32;
    const int t = threadIdx.x;
    const int w = t >> 6, lane = t & 63;
    const int lr = lane & 15, q = lane >> 4;
    const int bx = blockIdx.x;
    const bool qk = bx < 4;
    const int m0 = blockIdx.y * 128;
    const int n0 = (qk ? bx : bx - 4) * 128;
    const int mw = (w & 1) * 64, nw = (w >> 1) * 64;
    f32x4 acc[4][4] = {};

    const int s0i = t, s1i = 256 + t;
    const int c0 = s0i >> 7, r0 = s0i & 127;
    const int c1 = s1i >> 7, r1 = s1i & 127;
    const size_t oA0 = (size_t)(m0 + r0) * K + c0 * 8;
    const size_t oA1 = (size_t)(m0 + r1) * K + c1 * 8;
    const size_t oB0 = (size_t)(n0 + r0) * K + c0 * 8;
    const size_t oB1 = (size_t)(n0 + r1) * K + c1 * 8;
    const int ldsA = (w * 64) * 8, ldsB = (256 + w * 64) * 8;
    const bf16_t* Bhi = qk ? Bh : WvT;

    auto stage = [&](int bf, int k0) {
        gld16(Ah + oA0 + k0, &AsH[bf][ldsA]);
        gld16(Ah + oA1 + k0, &AsH[bf][ldsB]);
        gld16(Bhi + oB0 + k0, &BsH[bf][ldsA]);
        gld16(Bhi + oB1 + k0, &BsH[bf][ldsB]);
        if (qk) {
            gld16(Al + oA0 + k0, &AsL[bf][ldsA]);
            gld16(Al + oA1 + k0, &AsL[bf][ldsB]);
            gld16(Bl + oB0 + k0, &BsL[bf][ldsA]);
            gld16(Bl + oB1 + k0, &BsL[bf][ldsB]);
        }
    };

    stage(0, 0);
    __syncthreads();
    for (int it = 0; it < nk; ++it) {
        const int cur = it & 1;
        if (it + 1 < nk) stage(cur ^ 1, (it + 1) * 32);
        if (qk) {
            bf16x8 ah[4], al[4], bh[4], bl[4];
#pragma unroll
            for (int i = 0; i < 4; ++i) {
                int sa = (q * 128 + mw + i * 16 + lr) * 8;
                ah[i] = *(const bf16x8*)&AsH[cur][sa];
                al[i] = *(const bf16x8*)&AsL[cur][sa];
            }
#pragma unroll
            for (int j = 0; j < 4; ++j) {
                int sb = (q * 128 + nw + j * 16 + lr) * 8;
                bh[j] = *(const bf16x8*)&BsH[cur][sb];
                bl[j] = *(const bf16x8*)&BsL[cur][sb];
            }
#pragma unroll
            for (int i = 0; i < 4; ++i)
#pragma unroll
                for (int j = 0; j < 4; ++j) {
                    acc[i][j] = MFMA16(ah[i], bh[j], acc[i][j]);
                    acc[i][j] = MFMA16(ah[i], bl[j], acc[i][j]);
                    acc[i][j] = MFMA16(al[i], bh[j], acc[i][j]);
                }
        } else {
            bf16x8 af[4], bfv[4];
#pragma unroll
            for (int i = 0; i < 4; ++i)
                af[i] = *(const bf16x8*)&AsH[cur][(q * 128 + mw + i * 16 + lr) * 8];
#pragma unroll
            for (int j = 0; j < 4; ++j)
                bfv[j] = *(const bf16x8*)&BsH[cur][(q * 128 + nw + j * 16 + lr) * 8];
#pragma unroll
            for (int i = 0; i < 4; ++i)
#pragma unroll
                for (int j = 0; j < 4; ++j) acc[i][j] = MFMA16(af[i], bfv[j], acc[i][j]);
        }
        __syncthreads();
    }

#pragma unroll
    for (int i = 0; i < 4; ++i) {
        int row = m0 + mw + i * 16 + q * 4;  // token
#pragma unroll
        for (int j = 0; j < 4; ++j) {
            int col = n0 + nw + j * 16 + lr;
#pragma unroll
            for (int reg = 0; reg < 4; ++reg) {
                float x = acc[i][j][reg];
                int token = row + reg;
                if (qk) {
                    bf16_t hi = (bf16_t)x;
                    bf16_t lo = (bf16_t)(x - (float)hi);
                    if (col < 256) {
                        size_t o = (size_t)token * 256 + col;
                        Qhi[o] = hi;
                        Qlo[o] = lo;
                    } else {
                        int hc = col - 256;
                        int h = hc >> 6, d = hc & 63;
                        int b = token >> 11, s = token & 2047;
                        int it2 = s >> 6, sl = s & 63;
                        size_t o = ((size_t)((b * 4 + h) * 32 + it2)) * 4096 +
                                   (size_t)((d >> 3) * 64 + sl) * 8 + (d & 7);
                        Kbh[o] = hi;
                        Kbl[o] = lo;
                    }
                } else {
                    int vg = col;
                    int h = (vg >> 6) & 3, g = vg >> 8, d = vg & 63;
                    int b = token >> 11, s = token & 2047;
                    int it2 = s >> 6, sc = (s >> 3) & 7, si = s & 7;
                    size_t o = ((size_t)((b * 4 + h) * 32 + it2)) * 16384 +
                               (size_t)(sc * 256 + g * 64 + d) * 8 + si;
                    Vb[o] = (bf16_t)x;
                }
            }
        }
    }
}

// ---------------- plain bf16 GEMM (output projection) ----------------
__global__ __launch_bounds__(256, 1) void gemm_out(const bf16_t* __restrict__ A,
                                                   const bf16_t* __restrict__ BT,
                                                   float* __restrict__ C,
                                                   int M, int N, int K) {
    __shared__ bf16_t As[2][4096];
    __shared__ bf16_t Bs[2][4096];
    const int t = threadIdx.x;
    const int w = t >> 6, lane = t & 63;
    const int lr = lane & 15, q = lane >> 4;
    const int m0 = blockIdx.y * 128, n0 = blockIdx.x * 128;
    const int mw = (w & 1) * 64, nw = (w >> 1) * 64;
    f32x4 acc[4][4] = {};
    const int nk = K >> 5;

    const int s0i = t, s1i = 256 + t;
    const int c0 = s0i >> 7, r0 = s0i & 127;
    const int c1 = s1i >> 7, r1 = s1i & 127;
    const bf16_t* gA0 = A + (size_t)(m0 + r0) * K + c0 * 8;
    const bf16_t* gA1 = A + (size_t)(m0 + r1) * K + c1 * 8;
    const bf16_t* gB0 = BT + (size_t)(n0 + r0) * K + c0 * 8;
    const bf16_t* gB1 = BT + (size_t)(n0 + r1) * K + c1 * 8;
    const int ldsA = (w * 64) * 8, ldsB = (256 + w * 64) * 8;

    auto stage = [&](int bf, int k0) {
        gld16(gA0 + k0, &As[bf][ldsA]);
        gld16(gA1 + k0, &As[bf][ldsB]);
        gld16(gB0 + k0, &Bs[bf][ldsA]);
        gld16(gB1 + k0, &Bs[bf][ldsB]);
    };

    stage(0, 0);
    __syncthreads();
    for (int it = 0; it < nk; ++it) {
        const int cur = it & 1;
        if (it + 1 < nk) stage(cur ^ 1, (it + 1) * 32);
        bf16x8 af[4], bfv[4];
#pragma unroll
        for (int i = 0; i < 4; ++i)
            af[i] = *(const bf16x8*)&As[cur][(q * 128 + mw + i * 16 + lr) * 8];
#pragma unroll
        for (int j = 0; j < 4; ++j)
            bfv[j] = *(const bf16x8*)&Bs[cur][(q * 128 + nw + j * 16 + lr) * 8];
#pragma unroll
        for (int i = 0; i < 4; ++i)
#pragma unroll
            for (int j = 0; j < 4; ++j) acc[i][j] = MFMA16(af[i], bfv[j], acc[i][j]);
        __syncthreads();
    }

#pragma unroll
    for (int i = 0; i < 4; ++i) {
        int row = m0 + mw + i * 16 + q * 4;
#pragma unroll
        for (int j = 0; j < 4; ++j) {
            int col = n0 + nw + j * 16 + lr;
#pragma unroll
            for (int reg = 0; reg < 4; ++reg)
                C[(size_t)(row + reg) * N + col] = acc[i][j][reg];
        }
    }
}

// ---------------- flash attention, online softmax (R4-verified loop) ----------------
// grid 256 = b(2) x h(4) x qtile(16 of 128 rows) x shalf(2); 8 waves x 16 q-rows.
// Writes normalized partial O (bf16, ctx layout) + Sml = m + log(l) per row.
__global__ __launch_bounds__(512, 1) void attn_mfma(const bf16_t* __restrict__ Qhi,
                                                    const bf16_t* __restrict__ Qlo,
                                                    const bf16_t* __restrict__ Kbh,
                                                    const bf16_t* __restrict__ Kbl,
                                                    const bf16_t* __restrict__ Vb,
                                                    const float* __restrict__ btab,
                                                    bf16_t* __restrict__ part0,
                                                    bf16_t* __restrict__ part1,
                                                    float* __restrict__ Sml) {
    __shared__ bf16_t Kh[2][4096], Kl[2][4096], Vsm[2][16384], Ps[8192];
    const int t = threadIdx.x, w = t >> 6, lane = t & 63;
    const int lr = lane & 15, q = lane >> 4;
    const int blk = blockIdx.x;
    const int half = blk & 1, qt = (blk >> 1) & 15, h = (blk >> 5) & 3, b = blk >> 7;
    const int n0 = qt * 128;
    const int rowbase = n0 + w * 16;  // within batch

    const size_t qrow = (size_t)(b * 2048 + rowbase + lr) * 256 + h * 64;
    bf16x8 aqh[2], aql[2];
#pragma unroll
    for (int kb = 0; kb < 2; ++kb) {
        aqh[kb] = *(const bf16x8*)(Qhi + qrow + kb * 32 + q * 8);
        aql[kb] = *(const bf16x8*)(Qlo + qrow + kb * 32 + q * 8);
    }

    const int tilebase = (b * 4 + h) * 32 + half * 16;
    const bf16_t* gK = Kbh + (size_t)tilebase * 4096;
    const bf16_t* gL = Kbl + (size_t)tilebase * 4096;
    const bf16_t* gV = Vb + (size_t)tilebase * 16384;
    const float* btabh = btab + h * 4608 + 2047;

    auto stage = [&](int bf, int it) {
        gld16(gK + (size_t)it * 4096 + t * 8, &Kh[bf][t * 8]);
        gld16(gL + (size_t)it * 4096 + t * 8, &Kl[bf][t * 8]);
        const bf16_t* v0 = gV + (size_t)it * 16384;
#pragma unroll
        for (int j = 0; j < 4; ++j)
            gld16(v0 + (j * 512 + t) * 8, &Vsm[bf][(j * 512 + t) * 8]);
    };

    float m_r[4], l_r[4];
#pragma unroll
    for (int reg = 0; reg < 4; ++reg) { m_r[reg] = -INFINITY; l_r[reg] = 0.f; }
    f32x4 O[16] = {};

    stage(0, 0);
    __syncthreads();
    for (int it = 0; it < 16; ++it) {
        const int cur = it & 1;
        if (it + 1 < 16) stage(cur ^ 1, it + 1);
        const int s0g = half * 1024 + it * 64;

        // scores (hi/lo split)
        f32x4 sc[4];
#pragma unroll
        for (int ct = 0; ct < 4; ++ct) {
            f32x4 z = {0.f, 0.f, 0.f, 0.f};
#pragma unroll
            for (int kb = 0; kb < 2; ++kb) {
                int sb = ((kb * 4 + q) * 64 + ct * 16 + lr) * 8;
                bf16x8 bh = *(const bf16x8*)&Kh[cur][sb];
                bf16x8 bl = *(const bf16x8*)&Kl[cur][sb];
                z = MFMA16(aqh[kb], bh, z);
                z = MFMA16(aqh[kb], bl, z);
                z = MFMA16(aql[kb], bh, z);
            }
            sc[ct] = z;
        }
        // bias: delta = (s0g+ct*16+lr) - (rowbase+q*4+reg)
        const int dbase = (s0g + lr) - (rowbase + q * 4);
#pragma unroll
        for (int ct = 0; ct < 4; ++ct)
#pragma unroll
            for (int reg = 0; reg < 4; ++reg)
                sc[ct][reg] += btabh[dbase + ct * 16 - reg];

        // online softmax (rows wave-local; 16-lane col groups)
        float rm[4];
#pragma unroll
        for (int reg = 0; reg < 4; ++reg)
            rm[reg] = fmaxf(fmaxf(sc[0][reg], sc[1][reg]), fmaxf(sc[2][reg], sc[3][reg]));
#pragma unroll
        for (int off = 1; off < 16; off <<= 1)
#pragma unroll
            for (int reg = 0; reg < 4; ++reg)
                rm[reg] = fmaxf(rm[reg], __shfl_xor(rm[reg], off, 64));

        float alpha[4], rs[4];
#pragma unroll
        for (int reg = 0; reg < 4; ++reg) {
            float mo = m_r[reg];
            float mn = fmaxf(mo, rm[reg]);
            alpha[reg] = __expf(mo - mn);
            m_r[reg] = mn;
            rs[reg] = 0.f;
        }
#pragma unroll
        for (int ct = 0; ct < 4; ++ct) {
#pragma unroll
            for (int reg = 0; reg < 4; ++reg) {
                float p = __expf(sc[ct][reg] - m_r[reg]);
                rs[reg] += p;
                int col = ct * 16 + lr;
                Ps[((w * 128 + (col >> 3) * 16) + q * 4 + reg) * 8 + (col & 7)] = (bf16_t)p;
            }
        }
#pragma unroll
        for (int off = 1; off < 16; off <<= 1)
#pragma unroll
            for (int reg = 0; reg < 4; ++reg) rs[reg] += __shfl_xor(rs[reg], off, 64);
#pragma unroll
        for (int reg = 0; reg < 4; ++reg) l_r[reg] = l_r[reg] * alpha[reg] + rs[reg];

        // P A-fragments (wave-private LDS region)
        bf16x8 pa[2];
#pragma unroll
        for (int kb = 0; kb < 2; ++kb)
            pa[kb] = *(const bf16x8*)&Ps[(w * 128 + (kb * 4 + q) * 16 + lr) * 8];

        // O = alpha*O + P @ V
#pragma unroll
        for (int nt = 0; nt < 16; ++nt) {
            f32x4 o = O[nt];
#pragma unroll
            for (int reg = 0; reg < 4; ++reg) o[reg] *= alpha[reg];
#pragma unroll
            for (int kb = 0; kb < 2; ++kb) {
                bf16x8 v = *(const bf16x8*)&Vsm[cur][((kb * 4 + q) * 256 + nt * 16 + lr) * 8];
                o = MFMA16(pa[kb], v, o);
            }
            O[nt] = o;
        }
        __syncthreads();
    }

    // epilogue: normalized partial O + per-row m+log(l)
    bf16_t* P = half ? part1 : part0;
    float inv[4];
#pragma unroll
    for (int reg = 0; reg < 4; ++reg) inv[reg] = 1.f / l_r[reg];
    const size_t tokbase = (size_t)(b * 2048 + rowbase + q * 4);
#pragma unroll
    for (int nt = 0; nt < 16; ++nt) {
        int v = nt * 16 + lr;
        int vg = ((v >> 6) * 4 + h) * 64 + (v & 63);
#pragma unroll
        for (int reg = 0; reg < 4; ++reg)
            P[(tokbase + reg) * 1024 + vg] = (bf16_t)(O[nt][reg] * inv[reg]);
    }
    if (lr == 0) {
#pragma unroll
        for (int reg = 0; reg < 4; ++reg)
            Sml[half * 16384 + (tokbase + reg) * 4 + h] = m_r[reg] + logf(l_r[reg]);
    }
}

// ---------------- combine the two s-halves (in-place into part0) ----------------
__global__ __launch_bounds__(256) void combine_halves(bf16_t* __restrict__ p0,
                                                      const bf16_t* __restrict__ p1,
                                                      const float* __restrict__ Sml) {
    size_t flat = ((size_t)blockIdx.x * 256 + threadIdx.x) * 8;
    int tok = (int)(flat >> 10), c = (int)(flat & 1023), h = (c >> 6) & 3;
    float s0 = Sml[tok * 4 + h], s1 = Sml[16384 + tok * 4 + h];
    float M = fmaxf(s0, s1);
    float e0 = __expf(s0 - M), e1 = __expf(s1 - M);
    float r = 1.f / (e0 + e1);
    float w0 = e0 * r, w1 = e1 * r;
    bf16x8 a = *(bf16x8*)(p0 + flat);
    bf16x8 bb = *(const bf16x8*)(p1 + flat);
    bf16x8 o;
#pragma unroll
    for (int i = 0; i < 8; ++i) o[i] = (bf16_t)(w0 * (float)a[i] + w1 * (float)bb[i]);
    *(bf16x8*)(p0 + flat) = o;
}

extern "C" void kernel_launch(void* const* d_in, const int* in_sizes, int n_in,
                              void* d_out, int out_size, void* d_ws, size_t ws_size,
                              hipStream_t stream) {
    const float* hs = (const float*)d_in[0];
    const float* Wq = (const float*)d_in[1];
    const float* Wk = (const float*)d_in[2];
    const float* Wv = (const float*)d_in[3];
    const float* Wo = (const float*)d_in[4];
    const float* rb = (const float*)d_in[5];
    float* out = (float*)d_out;

    const size_t MB = 1 << 20;
    const size_t KB = 1 << 10;
    char* ws = (char*)d_ws;
    // Tight map (peak 38.25 MB), NO alias between proj inputs and proj outputs:
    //   0-8    hs_hi   (dead after proj) -> part0 -> ctx (combine in-place)
    //   8-16   hs_lo   (dead after proj) -> part1 (attn output; attn never reads hs_lo)
    //   16-17  WqkThi  | 17-18 WqkTlo | 18-20 WvT | 20-22 WoT (WoT live to end)
    //   22     btab (72KB, pad 128KB) | +128KB Sml (128KB)
    //   22.25-30.25  Qhi/Qlo/Kbh/Kbl (2MB each)
    //   30.25-38.25  Vb  (own region — fixes the R5/R6 WAR race)
    bf16_t* hs_hi = (bf16_t*)(ws);
    bf16_t* hs_lo = (bf16_t*)(ws + 8 * MB);
    bf16_t* WqkThi = (bf16_t*)(ws + 16 * MB);
    bf16_t* WqkTlo = (bf16_t*)(ws + 17 * MB);
    bf16_t* WvT = (bf16_t*)(ws + 18 * MB);
    bf16_t* WoT = (bf16_t*)(ws + 20 * MB);
    float* btab = (float*)(ws + 22 * MB);
    float* Sml = (float*)(ws + 22 * MB + 128 * KB);
    bf16_t* Qhi = (bf16_t*)(ws + 22 * MB + 256 * KB);
    bf16_t* Qlo = Qhi + (size_t)4096 * 256;
    bf16_t* Kbh = Qlo + (size_t)4096 * 256;
    bf16_t* Kbl = Kbh + (size_t)4096 * 256;
    bf16_t* Vb = Kbl + (size_t)4096 * 256;  // 8 MB, ends at 38.25 MB
    bf16_t* part0 = hs_hi;
    bf16_t* part1 = hs_lo;

    prep_all<<<7184, 256, 0, stream>>>(hs, Wq, Wk, Wv, Wo, rb, hs_hi, hs_lo, WqkThi,
                                       WqkTlo, WvT, WoT, btab);
    proj_qkv<<<dim3(12, 32), 256, 0, stream>>>(hs_hi, hs_lo, WqkThi, WqkTlo, WvT, Qhi,
                                               Qlo, Kbh, Kbl, Vb);
    attn_mfma<<<256, 512, 0, stream>>>(Qhi, Qlo, Kbh, Kbl, Vb, btab, part0, part1, Sml);
    combine_halves<<<2048, 256, 0, stream>>>(part0, part1, Sml);
    gemm_out<<<dim3(8, 32), 256, 0, stream>>>(part0, WoT, out, 4096, 1024, 1024);
}

// Round 8
// 241.041 us; speedup vs baseline: 5.4772x; 1.0907x over previous
//
#include <hip/hip_runtime.h>
#include <math.h>

// B=2, S=2048, D_MODEL=1024, D_KV=64, N_HEADS=16, KV_HEADS=4, G=4
// Pipeline (bf16 MFMA, fp32 accumulate):
//   prep_all: cast hs hi/lo; WqkT hi/lo; WvT/WoT bf16; bias table   (1 launch)
//   proj_qkv: 512 blocks (8 QK col-tiles 64-wide + 8 V col-tiles 128-wide) x 32 rows
//     48KB LDS pool -> 2 blocks/CU co-resident. Vb does NOT alias any proj input.
//   attn: 512-thr blocks, split-s x2, online softmax -> partials + m+log(l)
//   combine: softmax-weighted merge -> ctx bf16
//   gemm_out: 128x64 tiles, grid 512 -> fp32 out

typedef __bf16 bf16_t;
typedef bf16_t bf16x8 __attribute__((ext_vector_type(8)));
typedef bf16_t bf16x4 __attribute__((ext_vector_type(4)));
typedef float f32x4 __attribute__((ext_vector_type(4)));

#define MFMA16(a, b, c) __builtin_amdgcn_mfma_f32_16x16x32_bf16(a, b, c, 0, 0, 0)

typedef __attribute__((address_space(1))) void gvoid;
typedef __attribute__((address_space(3))) void svoid;
__device__ __forceinline__ void gld16(const void* g, void* l) {
    __builtin_amdgcn_global_load_lds((gvoid*)g, (svoid*)l, 16, 0, 0);
}

// ---------------- prep_all: fused block-range dispatch ----------------
__global__ __launch_bounds__(256) void prep_all(const float* __restrict__ hs,
                                                const float* __restrict__ Wq,
                                                const float* __restrict__ Wk,
                                                const float* __restrict__ Wv,
                                                const float* __restrict__ Wo,
                                                const float* __restrict__ rel_bias,
                                                bf16_t* __restrict__ hs_hi,
                                                bf16_t* __restrict__ hs_lo,
                                                bf16_t* __restrict__ Thi,
                                                bf16_t* __restrict__ Tlo,
                                                bf16_t* __restrict__ WvT,
                                                bf16_t* __restrict__ WoT,
                                                float* __restrict__ btab) {
    __shared__ float sm[2048];
    const int r = blockIdx.x, t = threadIdx.x;
    if (r < 4096) {
        size_t idx = ((size_t)r * 256 + t) * 4;
        float4 v = *(const float4*)(hs + idx);
        bf16x4 h, l;
        h[0] = (bf16_t)v.x; l[0] = (bf16_t)(v.x - (float)h[0]);
        h[1] = (bf16_t)v.y; l[1] = (bf16_t)(v.y - (float)h[1]);
        h[2] = (bf16_t)v.z; l[2] = (bf16_t)(v.z - (float)h[2]);
        h[3] = (bf16_t)v.w; l[3] = (bf16_t)(v.w - (float)h[3]);
        *(bf16x4*)(hs_hi + idx) = h;
        *(bf16x4*)(hs_lo + idx) = l;
    } else if (r < 5120) {
        int k = r - 4096;
        float* rq = sm;
        float* rk = sm + 1024;
#pragma unroll
        for (int j = 0; j < 4; ++j) {
            rq[t + j * 256] = Wq[(size_t)k * 1024 + t + j * 256];
            rk[t + j * 256] = Wk[(size_t)k * 1024 + t + j * 256];
        }
        __syncthreads();
        int h = t >> 6, j2 = t & 63;
        float sq = 0.f, sk = 0.f;
#pragma unroll
        for (int g = 0; g < 4; ++g) {
            sq += rq[(g * 4 + h) * 64 + j2];
            sk += rk[(g * 4 + h) * 64 + j2];
        }
        sk *= 0.25f;
        bf16_t qh = (bf16_t)sq;
        Thi[(size_t)t * 1024 + k] = qh;
        Tlo[(size_t)t * 1024 + k] = (bf16_t)(sq - (float)qh);
        bf16_t kh = (bf16_t)sk;
        Thi[(size_t)(256 + t) * 1024 + k] = kh;
        Tlo[(size_t)(256 + t) * 1024 + k] = (bf16_t)(sk - (float)kh);
    } else if (r < 7168) {
        const float* src = (r < 6144) ? Wv : Wo;
        bf16_t* dst = (r < 6144) ? WvT : WoT;
        int rr = (r < 6144) ? r - 5120 : r - 6144;
        int bx = (rr & 31) * 32, by = (rr >> 5) * 32;
        int tx = t & 31, ty = t >> 5;
        float(*tile)[33] = (float(*)[33])sm;
#pragma unroll
        for (int i = 0; i < 32; i += 8)
            tile[ty + i][tx] = src[(size_t)(by + ty + i) * 1024 + bx + tx];
        __syncthreads();
#pragma unroll
        for (int i = 0; i < 32; i += 8)
            dst[(size_t)(bx + ty + i) * 1024 + by + tx] = (bf16_t)tile[tx][ty + i];
    } else {
        int idx = (r - 7168) * 256 + t;
        if (idx >= 4095) return;
        int delta = idx - 2047;
        int bucket = (delta > 0) ? 16 : 0;
        int arp = delta < 0 ? -delta : delta;
        int rb;
        if (arp < 8) {
            rb = arp;
        } else {
            float tt = (logf((float)arp * 0.125f) / 2.772588722239781f) * 8.0f;
            int ri = 8 + (int)tt;
            rb = ri < 15 ? ri : 15;
        }
        bucket += rb;
#pragma unroll
        for (int h = 0; h < 4; ++h) {
            float s = 0.25f * (rel_bias[bucket * 16 + h] + rel_bias[bucket * 16 + h + 4] +
                               rel_bias[bucket * 16 + h + 8] + rel_bias[bucket * 16 + h + 12]);
            btab[h * 4608 + idx] = s;
        }
    }
}

// ---------------- fused projection GEMM, balanced 512-block grid ----------------
// bx<8:  QK col-tile 64-wide (hi/lo, 3 MFMAs), n0 = bx*64
// bx>=8: V col-tile 128-wide (plain),           n0 = (bx-8)*128
// 48KB LDS pool: [0,8K) AsH dbuf | [8K,16K) AsL dbuf | [16K,20K) BsH-qk dbuf |
//                [20K,24K) BsL-qk dbuf ; V overlays: As=[0,8K), Bs=[8K,16K)
__global__ __launch_bounds__(256, 1) void proj_qkv(const bf16_t* __restrict__ Ah,
                                                   const bf16_t* __restrict__ Al,
                                                   const bf16_t* __restrict__ Bh,
                                                   const bf16_t* __restrict__ Bl,
                                                   const bf16_t* __restrict__ WvT,
                                                   bf16_t* __restrict__ Qhi,
                                                   bf16_t* __restrict__ Qlo,
                                                   bf16_t* __restrict__ Kbh,
                                                   bf16_t* __restrict__ Kbl,
                                                   bf16_t* __restrict__ Vb) {
    __shared__ bf16_t pool[24576];  // 48KB
    const int K = 1024, nk = 32;
    const int t = threadIdx.x;
    const int w = t >> 6, lane = t & 63;
    const int lr = lane & 15, q = lane >> 4;
    const int bx = blockIdx.x;
    const bool qk = bx < 8;
    const int m0 = blockIdx.y * 128;
    const int n0 = qk ? bx * 64 : (bx - 8) * 128;
    const int mw = (w & 1) * 64;
    f32x4 acc[4][4] = {};

    // A staging (both paths): 128-row tile, slots = chunk*128 + row
    const int rA = t & 127, cA0 = t >> 7, cA1 = 2 + (t >> 7);
    const size_t oA0 = (size_t)(m0 + rA) * K + cA0 * 8;
    const size_t oA1 = (size_t)(m0 + rA) * K + cA1 * 8;
    // QK B staging: 64-row tile, slot = chunk*64 + row, chunk = t>>6
    const int rBq = t & 63, cBq = t >> 6;
    const size_t oBq = (size_t)(n0 + rBq) * K + cBq * 8;
    // V B staging: 128-row tile (same slot scheme as A)
    const size_t oBv0 = (size_t)(n0 + rA) * K + cA0 * 8;
    const size_t oBv1 = (size_t)(n0 + rA) * K + cA1 * 8;

    auto stage = [&](int bf, int k0) {
        gld16(Ah + oA0 + k0, &pool[bf * 4096 + t * 8]);
        gld16(Ah + oA1 + k0, &pool[bf * 4096 + (256 + t) * 8]);
        if (qk) {
            gld16(Al + oA0 + k0, &pool[8192 + bf * 4096 + t * 8]);
            gld16(Al + oA1 + k0, &pool[8192 + bf * 4096 + (256 + t) * 8]);
            gld16(Bh + oBq + k0, &pool[16384 + bf * 2048 + t * 8]);
            gld16(Bl + oBq + k0, &pool[20480 + bf * 2048 + t * 8]);
        } else {
            gld16(WvT + oBv0 + k0, &pool[8192 + bf * 4096 + t * 8]);
            gld16(WvT + oBv1 + k0, &pool[8192 + bf * 4096 + (256 + t) * 8]);
        }
    };

    stage(0, 0);
    __syncthreads();
    for (int it = 0; it < nk; ++it) {
        const int cur = it & 1;
        if (it + 1 < nk) stage(cur ^ 1, (it + 1) * 32);
        if (qk) {
            const int nw = (w >> 1) * 32;
            bf16x8 ah[4], al[4], bh[2], bl[2];
#pragma unroll
            for (int i = 0; i < 4; ++i) {
                int sa = (q * 128 + mw + i * 16 + lr) * 8;
                ah[i] = *(const bf16x8*)&pool[cur * 4096 + sa];
                al[i] = *(const bf16x8*)&pool[8192 + cur * 4096 + sa];
            }
#pragma unroll
            for (int j = 0; j < 2; ++j) {
                int sb = (q * 64 + nw + j * 16 + lr) * 8;
                bh[j] = *(const bf16x8*)&pool[16384 + cur * 2048 + sb];
                bl[j] = *(const bf16x8*)&pool[20480 + cur * 2048 + sb];
            }
#pragma unroll
            for (int i = 0; i < 4; ++i)
#pragma unroll
                for (int j = 0; j < 2; ++j) {
                    acc[i][j] = MFMA16(ah[i], bh[j], acc[i][j]);
                    acc[i][j] = MFMA16(ah[i], bl[j], acc[i][j]);
                    acc[i][j] = MFMA16(al[i], bh[j], acc[i][j]);
                }
        } else {
            const int nw = (w >> 1) * 64;
            bf16x8 af[4], bfv[4];
#pragma unroll
            for (int i = 0; i < 4; ++i)
                af[i] = *(const bf16x8*)&pool[cur * 4096 + (q * 128 + mw + i * 16 + lr) * 8];
#pragma unroll
            for (int j = 0; j < 4; ++j)
                bfv[j] =
                    *(const bf16x8*)&pool[8192 + cur * 4096 + (q * 128 + nw + j * 16 + lr) * 8];
#pragma unroll
            for (int i = 0; i < 4; ++i)
#pragma unroll
                for (int j = 0; j < 4; ++j) acc[i][j] = MFMA16(af[i], bfv[j], acc[i][j]);
        }
        __syncthreads();
    }

    const int nj = qk ? 2 : 4;
    const int nwq = qk ? (w >> 1) * 32 : (w >> 1) * 64;
#pragma unroll
    for (int i = 0; i < 4; ++i) {
        int row = m0 + mw + i * 16 + q * 4;  // token base
#pragma unroll 4
        for (int j = 0; j < nj; ++j) {
            int col = n0 + nwq + j * 16 + lr;
#pragma unroll
            for (int reg = 0; reg < 4; ++reg) {
                float x = acc[i][j][reg];
                int token = row + reg;
                if (qk) {
                    bf16_t hi = (bf16_t)x;
                    bf16_t lo = (bf16_t)(x - (float)hi);
                    if (col < 256) {
                        size_t o = (size_t)token * 256 + col;
                        Qhi[o] = hi;
                        Qlo[o] = lo;
                    } else {
                        int hc = col - 256;
                        int h = hc >> 6, d = hc & 63;
                        int b = token >> 11, s = token & 2047;
                        int it2 = s >> 6, sl = s & 63;
                        size_t o = ((size_t)((b * 4 + h) * 32 + it2)) * 4096 +
                                   (size_t)((d >> 3) * 64 + sl) * 8 + (d & 7);
                        Kbh[o] = hi;
                        Kbl[o] = lo;
                    }
                } else {
                    int vg = col;
                    int h = (vg >> 6) & 3, g = vg >> 8, d = vg & 63;
                    int b = token >> 11, s = token & 2047;
                    int it2 = s >> 6, sc = (s >> 3) & 7, si = s & 7;
                    size_t o = ((size_t)((b * 4 + h) * 32 + it2)) * 16384 +
                               (size_t)(sc * 256 + g * 64 + d) * 8 + si;
                    Vb[o] = (bf16_t)x;
                }
            }
        }
    }
}

// ---------------- output GEMM: 128x64 tiles, grid 512 ----------------
__global__ __launch_bounds__(256, 1) void gemm_out(const bf16_t* __restrict__ A,
                                                   const bf16_t* __restrict__ BT,
                                                   float* __restrict__ C,
                                                   int M, int N, int K) {
    __shared__ bf16_t pool[12288];  // 24KB: A dbuf [0,8K) elems, B dbuf [8192,12288)
    const int t = threadIdx.x;
    const int w = t >> 6, lane = t & 63;
    const int lr = lane & 15, q = lane >> 4;
    const int m0 = blockIdx.y * 128, n0 = blockIdx.x * 64;
    const int mw = (w & 1) * 64, nw = (w >> 1) * 32;
    f32x4 acc[4][2] = {};
    const int nk = K >> 5;

    const int rA = t & 127, cA0 = t >> 7, cA1 = 2 + (t >> 7);
    const bf16_t* gA0 = A + (size_t)(m0 + rA) * K + cA0 * 8;
    const bf16_t* gA1 = A + (size_t)(m0 + rA) * K + cA1 * 8;
    const bf16_t* gB = BT + (size_t)(n0 + (t & 63)) * K + (t >> 6) * 8;

    auto stage = [&](int bf, int k0) {
        gld16(gA0 + k0, &pool[bf * 4096 + t * 8]);
        gld16(gA1 + k0, &pool[bf * 4096 + (256 + t) * 8]);
        gld16(gB + k0, &pool[8192 + bf * 2048 + t * 8]);
    };

    stage(0, 0);
    __syncthreads();
    for (int it = 0; it < nk; ++it) {
        const int cur = it & 1;
        if (it + 1 < nk) stage(cur ^ 1, (it + 1) * 32);
        bf16x8 af[4], bfv[2];
#pragma unroll
        for (int i = 0; i < 4; ++i)
            af[i] = *(const bf16x8*)&pool[cur * 4096 + (q * 128 + mw + i * 16 + lr) * 8];
#pragma unroll
        for (int j = 0; j < 2; ++j)
            bfv[j] = *(const bf16x8*)&pool[8192 + cur * 2048 + (q * 64 + nw + j * 16 + lr) * 8];
#pragma unroll
        for (int i = 0; i < 4; ++i)
#pragma unroll
            for (int j = 0; j < 2; ++j) acc[i][j] = MFMA16(af[i], bfv[j], acc[i][j]);
        __syncthreads();
    }

#pragma unroll
    for (int i = 0; i < 4; ++i) {
        int row = m0 + mw + i * 16 + q * 4;
#pragma unroll
        for (int j = 0; j < 2; ++j) {
            int col = n0 + nw + j * 16 + lr;
#pragma unroll
            for (int reg = 0; reg < 4; ++reg)
                C[(size_t)(row + reg) * N + col] = acc[i][j][reg];
        }
    }
}

// ---------------- flash attention, online softmax (verified) ----------------
__global__ __launch_bounds__(512, 1) void attn_mfma(const bf16_t* __restrict__ Qhi,
                                                    const bf16_t* __restrict__ Qlo,
                                                    const bf16_t* __restrict__ Kbh,
                                                    const bf16_t* __restrict__ Kbl,
                                                    const bf16_t* __restrict__ Vb,
                                                    const float* __restrict__ btab,
                                                    bf16_t* __restrict__ part0,
                                                    bf16_t* __restrict__ part1,
                                                    float* __restrict__ Sml) {
    __shared__ bf16_t Kh[2][4096], Kl[2][4096], Vsm[2][16384], Ps[8192];
    const int t = threadIdx.x, w = t >> 6, lane = t & 63;
    const int lr = lane & 15, q = lane >> 4;
    const int blk = blockIdx.x;
    const int half = blk & 1, qt = (blk >> 1) & 15, h = (blk >> 5) & 3, b = blk >> 7;
    const int n0 = qt * 128;
    const int rowbase = n0 + w * 16;

    const size_t qrow = (size_t)(b * 2048 + rowbase + lr) * 256 + h * 64;
    bf16x8 aqh[2], aql[2];
#pragma unroll
    for (int kb = 0; kb < 2; ++kb) {
        aqh[kb] = *(const bf16x8*)(Qhi + qrow + kb * 32 + q * 8);
        aql[kb] = *(const bf16x8*)(Qlo + qrow + kb * 32 + q * 8);
    }

    const int tilebase = (b * 4 + h) * 32 + half * 16;
    const bf16_t* gK = Kbh + (size_t)tilebase * 4096;
    const bf16_t* gL = Kbl + (size_t)tilebase * 4096;
    const bf16_t* gV = Vb + (size_t)tilebase * 16384;
    const float* btabh = btab + h * 4608 + 2047;

    auto stage = [&](int bf, int it) {
        gld16(gK + (size_t)it * 4096 + t * 8, &Kh[bf][t * 8]);
        gld16(gL + (size_t)it * 4096 + t * 8, &Kl[bf][t * 8]);
        const bf16_t* v0 = gV + (size_t)it * 16384;
#pragma unroll
        for (int j = 0; j < 4; ++j)
            gld16(v0 + (j * 512 + t) * 8, &Vsm[bf][(j * 512 + t) * 8]);
    };

    float m_r[4], l_r[4];
#pragma unroll
    for (int reg = 0; reg < 4; ++reg) { m_r[reg] = -INFINITY; l_r[reg] = 0.f; }
    f32x4 O[16] = {};

    stage(0, 0);
    __syncthreads();
    for (int it = 0; it < 16; ++it) {
        const int cur = it & 1;
        if (it + 1 < 16) stage(cur ^ 1, it + 1);
        const int s0g = half * 1024 + it * 64;

        f32x4 sc[4];
#pragma unroll
        for (int ct = 0; ct < 4; ++ct) {
            f32x4 z = {0.f, 0.f, 0.f, 0.f};
#pragma unroll
            for (int kb = 0; kb < 2; ++kb) {
                int sb = ((kb * 4 + q) * 64 + ct * 16 + lr) * 8;
                bf16x8 bh = *(const bf16x8*)&Kh[cur][sb];
                bf16x8 bl = *(const bf16x8*)&Kl[cur][sb];
                z = MFMA16(aqh[kb], bh, z);
                z = MFMA16(aqh[kb], bl, z);
                z = MFMA16(aql[kb], bh, z);
            }
            sc[ct] = z;
        }
        const int dbase = (s0g + lr) - (rowbase + q * 4);
#pragma unroll
        for (int ct = 0; ct < 4; ++ct)
#pragma unroll
            for (int reg = 0; reg < 4; ++reg)
                sc[ct][reg] += btabh[dbase + ct * 16 - reg];

        float rm[4];
#pragma unroll
        for (int reg = 0; reg < 4; ++reg)
            rm[reg] = fmaxf(fmaxf(sc[0][reg], sc[1][reg]), fmaxf(sc[2][reg], sc[3][reg]));
#pragma unroll
        for (int off = 1; off < 16; off <<= 1)
#pragma unroll
            for (int reg = 0; reg < 4; ++reg)
                rm[reg] = fmaxf(rm[reg], __shfl_xor(rm[reg], off, 64));

        float alpha[4], rs[4];
#pragma unroll
        for (int reg = 0; reg < 4; ++reg) {
            float mo = m_r[reg];
            float mn = fmaxf(mo, rm[reg]);
            alpha[reg] = __expf(mo - mn);
            m_r[reg] = mn;
            rs[reg] = 0.f;
        }
#pragma unroll
        for (int ct = 0; ct < 4; ++ct) {
#pragma unroll
            for (int reg = 0; reg < 4; ++reg) {
                float p = __expf(sc[ct][reg] - m_r[reg]);
                rs[reg] += p;
                int col = ct * 16 + lr;
                Ps[((w * 128 + (col >> 3) * 16) + q * 4 + reg) * 8 + (col & 7)] = (bf16_t)p;
            }
        }
#pragma unroll
        for (int off = 1; off < 16; off <<= 1)
#pragma unroll
            for (int reg = 0; reg < 4; ++reg) rs[reg] += __shfl_xor(rs[reg], off, 64);
#pragma unroll
        for (int reg = 0; reg < 4; ++reg) l_r[reg] = l_r[reg] * alpha[reg] + rs[reg];

        bf16x8 pa[2];
#pragma unroll
        for (int kb = 0; kb < 2; ++kb)
            pa[kb] = *(const bf16x8*)&Ps[(w * 128 + (kb * 4 + q) * 16 + lr) * 8];

#pragma unroll
        for (int nt = 0; nt < 16; ++nt) {
            f32x4 o = O[nt];
#pragma unroll
            for (int reg = 0; reg < 4; ++reg) o[reg] *= alpha[reg];
#pragma unroll
            for (int kb = 0; kb < 2; ++kb) {
                bf16x8 v = *(const bf16x8*)&Vsm[cur][((kb * 4 + q) * 256 + nt * 16 + lr) * 8];
                o = MFMA16(pa[kb], v, o);
            }
            O[nt] = o;
        }
        __syncthreads();
    }

    bf16_t* P = half ? part1 : part0;
    float inv[4];
#pragma unroll
    for (int reg = 0; reg < 4; ++reg) inv[reg] = 1.f / l_r[reg];
    const size_t tokbase = (size_t)(b * 2048 + rowbase + q * 4);
#pragma unroll
    for (int nt = 0; nt < 16; ++nt) {
        int v = nt * 16 + lr;
        int vg = ((v >> 6) * 4 + h) * 64 + (v & 63);
#pragma unroll
        for (int reg = 0; reg < 4; ++reg)
            P[(tokbase + reg) * 1024 + vg] = (bf16_t)(O[nt][reg] * inv[reg]);
    }
    if (lr == 0) {
#pragma unroll
        for (int reg = 0; reg < 4; ++reg)
            Sml[half * 16384 + (tokbase + reg) * 4 + h] = m_r[reg] + logf(l_r[reg]);
    }
}

// ---------------- combine the two s-halves (in-place into part0) ----------------
__global__ __launch_bounds__(256) void combine_halves(bf16_t* __restrict__ p0,
                                                      const bf16_t* __restrict__ p1,
                                                      const float* __restrict__ Sml) {
    size_t flat = ((size_t)blockIdx.x * 256 + threadIdx.x) * 8;
    int tok = (int)(flat >> 10), c = (int)(flat & 1023), h = (c >> 6) & 3;
    float s0 = Sml[tok * 4 + h], s1 = Sml[16384 + tok * 4 + h];
    float M = fmaxf(s0, s1);
    float e0 = __expf(s0 - M), e1 = __expf(s1 - M);
    float r = 1.f / (e0 + e1);
    float w0 = e0 * r, w1 = e1 * r;
    bf16x8 a = *(bf16x8*)(p0 + flat);
    bf16x8 bb = *(const bf16x8*)(p1 + flat);
    bf16x8 o;
#pragma unroll
    for (int i = 0; i < 8; ++i) o[i] = (bf16_t)(w0 * (float)a[i] + w1 * (float)bb[i]);
    *(bf16x8*)(p0 + flat) = o;
}

extern "C" void kernel_launch(void* const* d_in, const int* in_sizes, int n_in,
                              void* d_out, int out_size, void* d_ws, size_t ws_size,
                              hipStream_t stream) {
    const float* hs = (const float*)d_in[0];
    const float* Wq = (const float*)d_in[1];
    const float* Wk = (const float*)d_in[2];
    const float* Wv = (const float*)d_in[3];
    const float* Wo = (const float*)d_in[4];
    const float* rb = (const float*)d_in[5];
    float* out = (float*)d_out;

    const size_t MB = 1 << 20;
    const size_t KB = 1 << 10;
    char* ws = (char*)d_ws;
    // Map (peak 38.25 MB). Vb does NOT alias any proj input (R5/R6 lesson).
    bf16_t* hs_hi = (bf16_t*)(ws);                    // dead after proj -> part0/ctx
    bf16_t* hs_lo = (bf16_t*)(ws + 8 * MB);           // dead after proj -> part1
    bf16_t* WqkThi = (bf16_t*)(ws + 16 * MB);
    bf16_t* WqkTlo = (bf16_t*)(ws + 17 * MB);
    bf16_t* WvT = (bf16_t*)(ws + 18 * MB);
    bf16_t* WoT = (bf16_t*)(ws + 20 * MB);
    float* btab = (float*)(ws + 22 * MB);
    float* Sml = (float*)(ws + 22 * MB + 128 * KB);
    bf16_t* Qhi = (bf16_t*)(ws + 22 * MB + 256 * KB);
    bf16_t* Qlo = Qhi + (size_t)4096 * 256;
    bf16_t* Kbh = Qlo + (size_t)4096 * 256;
    bf16_t* Kbl = Kbh + (size_t)4096 * 256;
    bf16_t* Vb = Kbl + (size_t)4096 * 256;  // own 8 MB region
    bf16_t* part0 = hs_hi;
    bf16_t* part1 = hs_lo;

    prep_all<<<7184, 256, 0, stream>>>(hs, Wq, Wk, Wv, Wo, rb, hs_hi, hs_lo, WqkThi,
                                       WqkTlo, WvT, WoT, btab);
    proj_qkv<<<dim3(16, 32), 256, 0, stream>>>(hs_hi, hs_lo, WqkThi, WqkTlo, WvT, Qhi,
                                               Qlo, Kbh, Kbl, Vb);
    attn_mfma<<<256, 512, 0, stream>>>(Qhi, Qlo, Kbh, Kbl, Vb, btab, part0, part1, Sml);
    combine_halves<<<2048, 256, 0, stream>>>(part0, part1, Sml);
    gemm_out<<<dim3(16, 32), 256, 0, stream>>>(part0, WoT, out, 4096, 1024, 1024);
}